// Round 2
// baseline (673.514 us; speedup 1.0000x reference)
//
#include <hip/hip_runtime.h>
#include <math.h>

// Sizes (fixed by the problem)
//   x: [8][64][256][256] f32 ; channels = 2 groups x 32
//   w1/w2: [2][32][32][32] f32 (re,im separate inputs)
#define PI2_256 0.0245436926061702596754894014318f  // 2*pi/256

// ---------------------------------------------------------------------------
// init: trig tables Tc[k][n] = cos(2 pi k n / 256), Ts = sin(...), k<32, n<256
// exact modular reduction (k*n mod 256) keeps args small & precise
// ---------------------------------------------------------------------------
__global__ __launch_bounds__(256) void init_tab(float* __restrict__ tc, float* __restrict__ ts) {
    int idx = blockIdx.x * 256 + threadIdx.x;   // 0..16383
    int k = idx >> 8, n = idx & 255;
    int m = (k * n) & 255;
    float s, c;
    sincosf(PI2_256 * (float)m, &s, &c);
    tc[idx] = c;
    ts[idx] = s;
}

// ---------------------------------------------------------------------------
// Stage W (fused): per block = one (b,g,x-row). DFT(W)->mix(w2)->iDFT(W)
// writes y1 into d_out (scratch; fully consumed by h_dft before final write)
// ---------------------------------------------------------------------------
__global__ __launch_bounds__(256) void stage_w(const float* __restrict__ x,
                                               const float* __restrict__ w2r,
                                               const float* __restrict__ w2i,
                                               float* __restrict__ y1) {
    __shared__ float tile[32 * 256];               // input row tile
    __shared__ float XrL[32 * 33], XiL[32 * 33];   // DFT result  [i][k], pad 33
    __shared__ float YrL[32 * 33], YiL[32 * 33];   // mixed       [o][k], pad 33

    const int bid  = blockIdx.x;
    const int xrow = bid & 255;
    const int g    = (bid >> 8) & 1;
    const int b    = bid >> 9;
    const int t    = threadIdx.x;

    const size_t chan0 = (size_t)(b * 64 + g * 32);          // first channel of this group
    const size_t base  = (chan0 * 256 + xrow) * 256;         // + i*65536 + w

    // ---- load 32x256 tile (float4, coalesced) ----
    {
        const int wq = t & 63, i0 = t >> 6;  // i0: 0..3
        #pragma unroll
        for (int r = 0; r < 8; ++r) {
            const int i = i0 + r * 4;
            float4 v = *(const float4*)(x + base + (size_t)i * 65536 + wq * 4);
            *(float4*)(tile + i * 256 + wq * 4) = v;
        }
    }
    __syncthreads();

    // ---- phase A: truncated DFT along W (unscaled sums) ----
    {
        const int k = t & 31, i4 = t >> 5;   // this thread: mode k, rows i4+{0,8,16,24}
        float sd, cd;
        sincosf(PI2_256 * (float)k, &sd, &cd);
        float c = 1.f, s = 0.f;
        float xr0 = 0, xr1 = 0, xr2 = 0, xr3 = 0;
        float xi0 = 0, xi1 = 0, xi2 = 0, xi3 = 0;
        const float* t0 = tile + i4 * 256;
        for (int w = 0; w < 256; ++w) {
            const float a0 = t0[w];
            const float a1 = t0[8 * 256 + w];
            const float a2 = t0[16 * 256 + w];
            const float a3 = t0[24 * 256 + w];
            xr0 += a0 * c; xi0 -= a0 * s;
            xr1 += a1 * c; xi1 -= a1 * s;
            xr2 += a2 * c; xi2 -= a2 * s;
            xr3 += a3 * c; xi3 -= a3 * s;
            const float cn = c * cd - s * sd;   // rotate phasor by 2*pi*k/256
            s = s * cd + c * sd;
            c = cn;
        }
        XrL[(i4     ) * 33 + k] = xr0;  XiL[(i4     ) * 33 + k] = xi0;
        XrL[(i4 +  8) * 33 + k] = xr1;  XiL[(i4 +  8) * 33 + k] = xi1;
        XrL[(i4 + 16) * 33 + k] = xr2;  XiL[(i4 + 16) * 33 + k] = xi2;
        XrL[(i4 + 24) * 33 + k] = xr3;  XiL[(i4 + 24) * 33 + k] = xi3;
    }
    __syncthreads();

    // ---- phase B: channel mix  Y[o,k] = sum_i X[i,k] * w2c[g,i,o,k] ----
    {
        const int k = t & 31, o4 = t >> 5;   // o = o4 + 8m
        float ar[4] = {0, 0, 0, 0}, ai[4] = {0, 0, 0, 0};
        const float* wrb = w2r + (size_t)g * 32 * 32 * 32 + k;  // + i*1024 + o*32
        const float* wib = w2i + (size_t)g * 32 * 32 * 32 + k;
        for (int i = 0; i < 32; ++i) {
            const float xr = XrL[i * 33 + k];
            const float xi = XiL[i * 33 + k];
            const int ib = i * 1024;
            #pragma unroll
            for (int m = 0; m < 4; ++m) {
                const int o = o4 + 8 * m;
                const float wr = wrb[ib + o * 32];
                const float wi = wib[ib + o * 32];
                ar[m] += xr * wr - xi * wi;
                ai[m] += xr * wi + xi * wr;
            }
        }
        #pragma unroll
        for (int m = 0; m < 4; ++m) {
            const int o = o4 + 8 * m;
            YrL[o * 33 + k] = ar[m];
            YiL[o * 33 + k] = ai[m];
        }
    }
    __syncthreads();

    // ---- phase C: inverse truncated rDFT; imag of DC discarded (pocketfft) ----
    {
        const int wq = t & 63, oc = t >> 6;  // o = oc + 4m ; w = wq*4 + j
        float c2[4], s2[4], cd[4], sd[4];
        #pragma unroll
        for (int j = 0; j < 4; ++j) {
            sincosf(PI2_256 * (float)(wq * 4 + j), &sd[j], &cd[j]);
            c2[j] = 2.f * cd[j];   // phasor at k=1, pre-scaled by 2
            s2[j] = 2.f * sd[j];
        }
        float acc[8][4];
        #pragma unroll
        for (int m = 0; m < 8; ++m) {
            const float v0 = YrL[(oc + 4 * m) * 33];   // DC: real part only, weight 1
            acc[m][0] = v0; acc[m][1] = v0; acc[m][2] = v0; acc[m][3] = v0;
        }
        for (int k = 1; k < 32; ++k) {
            #pragma unroll
            for (int m = 0; m < 8; ++m) {
                const int o = oc + 4 * m;
                const float yr = YrL[o * 33 + k];
                const float yi = YiL[o * 33 + k];
                #pragma unroll
                for (int j = 0; j < 4; ++j)
                    acc[m][j] += yr * c2[j] - yi * s2[j];
            }
            #pragma unroll
            for (int j = 0; j < 4; ++j) {
                const float cn = c2[j] * cd[j] - s2[j] * sd[j];
                s2[j] = s2[j] * cd[j] + c2[j] * sd[j];
                c2[j] = cn;
            }
        }
        const float sc = 1.f / 256.f;   // (1/16 fwd) * (1/16 inv)
        const size_t ob = (chan0 * 256 + xrow) * 256 + wq * 4;
        #pragma unroll
        for (int m = 0; m < 8; ++m) {
            const int o = oc + 4 * m;
            float4 v = make_float4(acc[m][0] * sc, acc[m][1] * sc,
                                   acc[m][2] * sc, acc[m][3] * sc);
            *(float4*)(y1 + ob + (size_t)o * 65536) = v;
        }
    }
}

// ---------------------------------------------------------------------------
// Stage H kernel 1: truncated DFT along H. block = (b,g,i); 1024 threads.
// X layout: [b][g][i][k][w]  (w contiguous -> everything coalesced)
// ---------------------------------------------------------------------------
__global__ __launch_bounds__(1024) void h_dft(const float* __restrict__ y1,
                                              const float* __restrict__ tc,
                                              const float* __restrict__ ts,
                                              float* __restrict__ Xr,
                                              float* __restrict__ Xi) {
    __shared__ float TcL[32 * 256], TsL[32 * 256];
    const int t = threadIdx.x;
    // stage 32KB+32KB trig tables: 2048 float4 each, 1024 threads -> 2 iters
    #pragma unroll
    for (int r = 0; r < 2; ++r) {
        const int f = t + r * 1024;               // float4 index, 2048 total
        *(float4*)(TcL + f * 4) = *(const float4*)(tc + f * 4);
        *(float4*)(TsL + f * 4) = *(const float4*)(ts + f * 4);
    }
    __syncthreads();

    const int bid = blockIdx.x;
    const int i = bid & 31, g = (bid >> 5) & 1, b = bid >> 6;
    const int wave = t >> 6, lane = t & 63;
    const int w  = lane + (wave & 3) * 64;        // 0..255
    const int kg = wave >> 2;                     // k = kg*8 + r

    const float* src = y1 + (size_t)((b * 2 + g) * 32 + i) * 65536;  // [h][w]
    float xr[8] = {0, 0, 0, 0, 0, 0, 0, 0};
    float xi[8] = {0, 0, 0, 0, 0, 0, 0, 0};

    for (int h4 = 0; h4 < 64; ++h4) {
        const float a0 = src[(h4 * 4 + 0) * 256 + w];
        const float a1 = src[(h4 * 4 + 1) * 256 + w];
        const float a2 = src[(h4 * 4 + 2) * 256 + w];
        const float a3 = src[(h4 * 4 + 3) * 256 + w];
        #pragma unroll
        for (int r = 0; r < 8; ++r) {
            const int k = kg * 8 + r;
            const float4 c4 = *(const float4*)(TcL + k * 256 + h4 * 4);
            const float4 s4 = *(const float4*)(TsL + k * 256 + h4 * 4);
            xr[r] += a0 * c4.x + a1 * c4.y + a2 * c4.z + a3 * c4.w;
            xi[r] -= a0 * s4.x + a1 * s4.y + a2 * s4.z + a3 * s4.w;
        }
    }
    const size_t obase = ((size_t)((b * 2 + g) * 32 + i) * 32) * 256 + w;  // + k*256
    #pragma unroll
    for (int r = 0; r < 8; ++r) {
        const int k = kg * 8 + r;
        Xr[obase + (size_t)k * 256] = xr[r];
        Xi[obase + (size_t)k * 256] = xi[r];
    }
}

// ---------------------------------------------------------------------------
// Stage H kernel 2: channel mix per (b,g,k):  Y[o,k,w] = sum_i X[i,k,w]*w1c
// Y layout: [b][g][o][k][w]
// ---------------------------------------------------------------------------
__global__ __launch_bounds__(256) void h_mix(const float* __restrict__ Xr,
                                             const float* __restrict__ Xi,
                                             const float* __restrict__ w1r,
                                             const float* __restrict__ w1i,
                                             float* __restrict__ Yr,
                                             float* __restrict__ Yi) {
    __shared__ float XrL[32 * 256], XiL[32 * 256];
    const int bid = blockIdx.x;
    const int k = bid & 31, g = (bid >> 5) & 1, b = bid >> 6;
    const int t = threadIdx.x;

    const size_t sbase = (((size_t)(b * 2 + g) * 32) * 32 + k) * 256;  // + i*8192 + w
    {
        const int wq = t & 63, i0 = t >> 6;
        #pragma unroll
        for (int r = 0; r < 8; ++r) {
            const int i = i0 + r * 4;
            *(float4*)(XrL + i * 256 + wq * 4) =
                *(const float4*)(Xr + sbase + (size_t)i * 8192 + wq * 4);
            *(float4*)(XiL + i * 256 + wq * 4) =
                *(const float4*)(Xi + sbase + (size_t)i * 8192 + wq * 4);
        }
    }
    __syncthreads();

    const int wq = t & 63, o4 = t >> 6;   // o = o4 + 4m
    float accr[8][4] = {}, acci[8][4] = {};
    const int wb = g * 32 * 32 * 32 + k;  // + i*1024 + o*32
    for (int i = 0; i < 32; ++i) {
        const float4 xr4 = *(const float4*)(XrL + i * 256 + wq * 4);
        const float4 xi4 = *(const float4*)(XiL + i * 256 + wq * 4);
        const int wbi = wb + i * 1024;
        #pragma unroll
        for (int m = 0; m < 8; ++m) {
            const int o = o4 + 4 * m;
            const float wr = w1r[wbi + o * 32];
            const float wi = w1i[wbi + o * 32];
            accr[m][0] += xr4.x * wr - xi4.x * wi;  acci[m][0] += xr4.x * wi + xi4.x * wr;
            accr[m][1] += xr4.y * wr - xi4.y * wi;  acci[m][1] += xr4.y * wi + xi4.y * wr;
            accr[m][2] += xr4.z * wr - xi4.z * wi;  acci[m][2] += xr4.z * wi + xi4.z * wr;
            accr[m][3] += xr4.w * wr - xi4.w * wi;  acci[m][3] += xr4.w * wi + xi4.w * wr;
        }
    }
    const size_t ob = (((size_t)(b * 2 + g) * 32) * 32 + k) * 256 + wq * 4;  // + o*8192
    #pragma unroll
    for (int m = 0; m < 8; ++m) {
        const int o = o4 + 4 * m;
        *(float4*)(Yr + ob + (size_t)o * 8192) =
            make_float4(accr[m][0], accr[m][1], accr[m][2], accr[m][3]);
        *(float4*)(Yi + ob + (size_t)o * 8192) =
            make_float4(acci[m][0], acci[m][1], acci[m][2], acci[m][3]);
    }
}

// ---------------------------------------------------------------------------
// Stage H kernel 3: inverse truncated rDFT along H. block = (b,g,o).
// out[b, g*32+o, h, w] = (1/256) * (Yr[0] + sum_{k>=1} 2*(Yr cos - Yi sin))
// ---------------------------------------------------------------------------
__global__ __launch_bounds__(256) void h_inv(const float* __restrict__ Yr,
                                             const float* __restrict__ Yi,
                                             float* __restrict__ out) {
    __shared__ float YrL[32 * 256], YiL[32 * 256];
    const int bid = blockIdx.x;
    const int o = bid & 31, g = (bid >> 5) & 1, b = bid >> 6;
    const int t = threadIdx.x;

    const size_t sbase = (((size_t)(b * 2 + g) * 32 + o) * 32) * 256;  // + k*256 + w
    {
        const int wq = t & 63, k0 = t >> 6;
        #pragma unroll
        for (int r = 0; r < 8; ++r) {
            const int k = k0 + r * 4;
            *(float4*)(YrL + k * 256 + wq * 4) =
                *(const float4*)(Yr + sbase + (size_t)k * 256 + wq * 4);
            *(float4*)(YiL + k * 256 + wq * 4) =
                *(const float4*)(Yi + sbase + (size_t)k * 256 + wq * 4);
        }
    }
    __syncthreads();

    const int wq = t & 63, h0 = t >> 6;   // h = h0 + 4*jj
    const size_t obase = ((size_t)(b * 64 + g * 32 + o) * 256) * 256 + wq * 4;  // + h*256
    const float4 y0 = *(const float4*)(YrL + wq * 4);   // k=0 row (real part only)
    const float sc = 1.f / 256.f;

    for (int jj = 0; jj < 64; ++jj) {
        const int h = h0 + jj * 4;
        float sd, cd;
        sincosf(PI2_256 * (float)h, &sd, &cd);
        float c2 = 2.f * cd, s2 = 2.f * sd;   // phasor at k=1, pre-scaled by 2
        float4 acc = y0;
        for (int k = 1; k < 32; ++k) {
            const float4 yr = *(const float4*)(YrL + k * 256 + wq * 4);
            const float4 yi = *(const float4*)(YiL + k * 256 + wq * 4);
            acc.x += yr.x * c2 - yi.x * s2;
            acc.y += yr.y * c2 - yi.y * s2;
            acc.z += yr.z * c2 - yi.z * s2;
            acc.w += yr.w * c2 - yi.w * s2;
            const float cn = c2 * cd - s2 * sd;
            s2 = s2 * cd + c2 * sd;
            c2 = cn;
        }
        float4 v = make_float4(acc.x * sc, acc.y * sc, acc.z * sc, acc.w * sc);
        *(float4*)(out + obase + (size_t)h * 256) = v;
    }
}

// ---------------------------------------------------------------------------
extern "C" void kernel_launch(void* const* d_in, const int* in_sizes, int n_in,
                              void* d_out, int out_size, void* d_ws, size_t ws_size,
                              hipStream_t stream) {
    const float* x   = (const float*)d_in[0];
    const float* w1r = (const float*)d_in[1];
    const float* w1i = (const float*)d_in[2];
    const float* w2r = (const float*)d_in[3];
    const float* w2i = (const float*)d_in[4];
    float* out = (float*)d_out;
    float* ws  = (float*)d_ws;

    float* tc = ws;                   // 16384 floats
    float* ts = ws + 16384;           // 16384 floats
    float* Xr = ws + 32768;           // 4,194,304 floats each
    float* Xi = Xr + 4194304;
    float* Yr = Xi + 4194304;
    float* Yi = Yr + 4194304;
    // total ws use: (32768 + 4*4194304)*4 B ~= 67.2 MB

    init_tab<<<64, 256, 0, stream>>>(tc, ts);
    // Stage W (fused), writes y1 into d_out (scratch)
    stage_w<<<4096, 256, 0, stream>>>(x, w2r, w2i, out);
    // Stage H: DFT -> mix -> inverse; final result overwrites d_out
    h_dft<<<512, 1024, 0, stream>>>(out, tc, ts, Xr, Xi);
    h_mix<<<512, 256, 0, stream>>>(Xr, Xi, w1r, w1i, Yr, Yi);
    h_inv<<<512, 256, 0, stream>>>(Yr, Yi, out);
}

// Round 3
// 390.925 us; speedup vs baseline: 1.7229x; 1.7229x over previous
//
#include <hip/hip_runtime.h>
#include <math.h>

// x: [8][64][256][256] f32 ; w1/w2: [2][32][32][32] f32 (re,im separate)
#define PI2_256 0.0245436926061702596754894014318f  // 2*pi/256

// ---------------------------------------------------------------------------
// trig tables tc[k][n] = cos(2 pi k n/256), ts = sin(...), k<32, n<256
// ---------------------------------------------------------------------------
__global__ __launch_bounds__(256) void init_tab(float* __restrict__ tc, float* __restrict__ ts) {
    int idx = blockIdx.x * 256 + threadIdx.x;   // 0..16383
    int k = idx >> 8, n = idx & 255;
    int m = (k * n) & 255;
    float s, c;
    sincosf(PI2_256 * (float)m, &s, &c);
    tc[idx] = c;
    ts[idx] = s;
}

// ---------------------------------------------------------------------------
// Stage W (fused): block = (b,g,xrow). DFT(W) -> mix(w2, scale folded) -> iDFT(W)
// ---------------------------------------------------------------------------
__global__ __launch_bounds__(256) void stage_w(const float* __restrict__ x,
                                               const float* __restrict__ w2r,
                                               const float* __restrict__ w2i,
                                               const float* __restrict__ tc,
                                               const float* __restrict__ ts,
                                               float* __restrict__ y1) {
    __shared__ float tile[32 * 256];                       // 32 KB
    __shared__ float XrL[32 * 36], XiL[32 * 36];           // [i][k], pad 36 (b128-aligned)
    __shared__ float YrL[32 * 36], YiL[32 * 36];           // [o][k], pad 36

    const int bid  = blockIdx.x;
    const int xrow = bid & 255;
    const int g    = (bid >> 8) & 1;
    const int b    = bid >> 9;
    const int t    = threadIdx.x;

    const size_t chan0 = (size_t)(b * 64 + g * 32);
    const size_t base  = (chan0 * 256 + xrow) * 256;       // + i*65536 + w

    // ---- stage input tile ----
    {
        const int wq = t & 63, i0 = t >> 6;
        #pragma unroll
        for (int r = 0; r < 8; ++r) {
            const int i = i0 + r * 4;
            *(float4*)(tile + i * 256 + wq * 4) =
                *(const float4*)(x + base + (size_t)i * 65536 + wq * 4);
        }
    }
    __syncthreads();

    // ---- phase A: truncated DFT along W (unscaled). k = t&31, rows i4+8r ----
    {
        const int k = t & 31, i4 = t >> 5;
        float sd, cd; sincosf(PI2_256 * (float)k, &sd, &cd);
        float c = 1.f, s = 0.f;                            // phasor at h=0
        float xr0 = 0, xr1 = 0, xr2 = 0, xr3 = 0;
        float xi0 = 0, xi1 = 0, xi2 = 0, xi3 = 0;
        for (int hq = 0; hq < 64; ++hq) {
            const float4 a0 = *(const float4*)(tile + (i4     ) * 256 + hq * 4);
            const float4 a1 = *(const float4*)(tile + (i4 +  8) * 256 + hq * 4);
            const float4 a2 = *(const float4*)(tile + (i4 + 16) * 256 + hq * 4);
            const float4 a3 = *(const float4*)(tile + (i4 + 24) * 256 + hq * 4);
            #pragma unroll
            for (int j = 0; j < 4; ++j) {
                const float e0 = (&a0.x)[j], e1 = (&a1.x)[j];
                const float e2 = (&a2.x)[j], e3 = (&a3.x)[j];
                xr0 += e0 * c; xi0 -= e0 * s;
                xr1 += e1 * c; xi1 -= e1 * s;
                xr2 += e2 * c; xi2 -= e2 * s;
                xr3 += e3 * c; xi3 -= e3 * s;
                const float cn = c * cd - s * sd;          // rotate by 2*pi*k/256
                s = s * cd + c * sd;
                c = cn;
            }
        }
        XrL[(i4     ) * 36 + k] = xr0;  XiL[(i4     ) * 36 + k] = xi0;
        XrL[(i4 +  8) * 36 + k] = xr1;  XiL[(i4 +  8) * 36 + k] = xi1;
        XrL[(i4 + 16) * 36 + k] = xr2;  XiL[(i4 + 16) * 36 + k] = xi2;
        XrL[(i4 + 24) * 36 + k] = xr3;  XiL[(i4 + 24) * 36 + k] = xi3;
    }
    __syncthreads();

    // ---- phase B: channel mix, k-quad per thread; fold ortho scale here ----
    // Y'[o][k] = sck * sum_i X[i][k]*w2c[g][i][o][k], sck = (k==0?1:2)/256
    {
        const int kq = t & 7, o = t >> 3;
        const int k4 = kq * 4;
        float4 ar = {0,0,0,0}, ai = {0,0,0,0};
        const float* wrb = w2r + (size_t)g * 32768 + o * 32 + k4;   // + i*1024
        const float* wib = w2i + (size_t)g * 32768 + o * 32 + k4;
        for (int i = 0; i < 32; ++i) {
            const float4 xr = *(const float4*)(XrL + i * 36 + k4);
            const float4 xi = *(const float4*)(XiL + i * 36 + k4);
            const float4 wr = *(const float4*)(wrb + i * 1024);
            const float4 wi = *(const float4*)(wib + i * 1024);
            ar.x += xr.x * wr.x - xi.x * wi.x;  ai.x += xr.x * wi.x + xi.x * wr.x;
            ar.y += xr.y * wr.y - xi.y * wi.y;  ai.y += xr.y * wi.y + xi.y * wr.y;
            ar.z += xr.z * wr.z - xi.z * wi.z;  ai.z += xr.z * wi.z + xi.z * wr.z;
            ar.w += xr.w * wr.w - xi.w * wi.w;  ai.w += xr.w * wi.w + xi.w * wr.w;
        }
        const float s2 = 2.f / 256.f, s1 = 1.f / 256.f;
        const float s0 = (k4 == 0) ? s1 : s2;
        float4 yr = make_float4(ar.x * s0, ar.y * s2, ar.z * s2, ar.w * s2);
        float4 yi = make_float4(ai.x * s0, ai.y * s2, ai.z * s2, ai.w * s2);
        *(float4*)(YrL + o * 36 + k4) = yr;
        *(float4*)(YiL + o * 36 + k4) = yi;
    }
    __syncthreads();

    // ---- phase C: inverse via trig tables (pure dot products, k=0..31) ----
    // out[o][w] = sum_k Yr'[o][k]*c[k][w] - Yi'[o][k]*s[k][w]
    {
        const int wq = t & 63, wave = t >> 6;              // o = wave + 4m
        float4 acc[8];
        #pragma unroll
        for (int m = 0; m < 8; ++m) acc[m] = make_float4(0, 0, 0, 0);
        for (int kp = 0; kp < 16; ++kp) {
            const int k2 = kp * 2;
            const float4 c0 = *(const float4*)(tc + (size_t)(k2    ) * 256 + wq * 4);
            const float4 s0 = *(const float4*)(ts + (size_t)(k2    ) * 256 + wq * 4);
            const float4 c1 = *(const float4*)(tc + (size_t)(k2 + 1) * 256 + wq * 4);
            const float4 s1 = *(const float4*)(ts + (size_t)(k2 + 1) * 256 + wq * 4);
            #pragma unroll
            for (int m = 0; m < 8; ++m) {
                const int o = wave + 4 * m;
                const float yr0 = YrL[o * 36 + k2],     yi0 = YiL[o * 36 + k2];
                const float yr1 = YrL[o * 36 + k2 + 1], yi1 = YiL[o * 36 + k2 + 1];
                acc[m].x += yr0 * c0.x - yi0 * s0.x + yr1 * c1.x - yi1 * s1.x;
                acc[m].y += yr0 * c0.y - yi0 * s0.y + yr1 * c1.y - yi1 * s1.y;
                acc[m].z += yr0 * c0.z - yi0 * s0.z + yr1 * c1.z - yi1 * s1.z;
                acc[m].w += yr0 * c0.w - yi0 * s0.w + yr1 * c1.w - yi1 * s1.w;
            }
        }
        #pragma unroll
        for (int m = 0; m < 8; ++m) {
            const int o = wave + 4 * m;
            *(float4*)(y1 + (chan0 + o) * 65536 + (size_t)xrow * 256 + wq * 4) = acc[m];
        }
    }
}

// ---------------------------------------------------------------------------
// Stage H kernel 1: truncated DFT along H with even/odd mirror symmetry.
// block = (b,g,i), 512 threads: w = t&255, k-half = t>>8 (16 k each).
// Xr[k] = sum_{h=0..127}(y[h]+y[(256-h)&255])c[k][h] - y[0] + (-1)^k y[128]
// Xi[k] = -sum_{h=0..127}(y[h]-y[(256-h)&255])s[k][h]
// ---------------------------------------------------------------------------
__global__ __launch_bounds__(512) void h_dft(const float* __restrict__ y1,
                                             const float* __restrict__ tc,
                                             const float* __restrict__ ts,
                                             float* __restrict__ Xr,
                                             float* __restrict__ Xi) {
    __shared__ float TcL[32 * 128], TsL[32 * 128];         // half tables, 16 KB each
    const int t = threadIdx.x;
    #pragma unroll
    for (int rep = 0; rep < 2; ++rep) {
        const int q = t + rep * 512;                       // quad id 0..1023
        const int k = q >> 5, hq = q & 31;
        *(float4*)(TcL + k * 128 + hq * 4) = *(const float4*)(tc + (size_t)k * 256 + hq * 4);
        *(float4*)(TsL + k * 128 + hq * 4) = *(const float4*)(ts + (size_t)k * 256 + hq * 4);
    }
    __syncthreads();

    const int bid = blockIdx.x;
    const int i = bid & 31, g = (bid >> 5) & 1, b = bid >> 6;
    const int w = t & 255, kh = t >> 8;                    // k = kh*16 + r

    const float* src = y1 + (size_t)((b * 2 + g) * 32 + i) * 65536 + w;
    const float y0 = src[0], y128 = src[128 * 256];

    float xr[16], xi[16];
    #pragma unroll
    for (int r = 0; r < 16; ++r) {                         // k = kh*16+r, (-1)^k = (-1)^r
        xr[r] = ((r & 1) ? -y128 : y128) - y0;
        xi[r] = 0.f;
    }

    const int kb = kh * 16;
    for (int hq = 0; hq < 32; ++hq) {
        float ye[4], yo[4];
        #pragma unroll
        for (int j = 0; j < 4; ++j) {
            const int h = hq * 4 + j;
            const float a = src[(size_t)h * 256];
            const float m = src[(size_t)((256 - h) & 255) * 256];
            ye[j] = a + m;
            yo[j] = a - m;
        }
        #pragma unroll
        for (int r = 0; r < 16; ++r) {
            const float4 c4 = *(const float4*)(TcL + (kb + r) * 128 + hq * 4);
            const float4 s4 = *(const float4*)(TsL + (kb + r) * 128 + hq * 4);
            xr[r] += ye[0] * c4.x + ye[1] * c4.y + ye[2] * c4.z + ye[3] * c4.w;
            xi[r] -= yo[0] * s4.x + yo[1] * s4.y + yo[2] * s4.z + yo[3] * s4.w;
        }
    }
    const size_t obase = (size_t)((b * 2 + g) * 32 + i) * 8192 + w;   // + k*256
    #pragma unroll
    for (int r = 0; r < 16; ++r) {
        Xr[obase + (size_t)(kb + r) * 256] = xr[r];
        Xi[obase + (size_t)(kb + r) * 256] = xi[r];
    }
}

// ---------------------------------------------------------------------------
// Stage H kernel 2: channel mix per (b,g,k); ortho scale folded here.
// Y'[o][k][w] = sck * sum_i X[i][k][w]*w1c ; sck = (k==0?1:2)/256
// ---------------------------------------------------------------------------
__global__ __launch_bounds__(256) void h_mix(const float* __restrict__ Xr,
                                             const float* __restrict__ Xi,
                                             const float* __restrict__ w1r,
                                             const float* __restrict__ w1i,
                                             float* __restrict__ Yr,
                                             float* __restrict__ Yi) {
    __shared__ float XrL[32 * 256], XiL[32 * 256];
    const int bid = blockIdx.x;
    const int k = bid & 31, g = (bid >> 5) & 1, b = bid >> 6;
    const int t = threadIdx.x;

    const size_t sbase = (((size_t)(b * 2 + g) * 32) * 32 + k) * 256;  // + i*8192 + w
    {
        const int wq = t & 63, i0 = t >> 6;
        #pragma unroll
        for (int r = 0; r < 8; ++r) {
            const int i = i0 + r * 4;
            *(float4*)(XrL + i * 256 + wq * 4) =
                *(const float4*)(Xr + sbase + (size_t)i * 8192 + wq * 4);
            *(float4*)(XiL + i * 256 + wq * 4) =
                *(const float4*)(Xi + sbase + (size_t)i * 8192 + wq * 4);
        }
    }
    __syncthreads();

    const int wq = t & 63, o4 = t >> 6;   // o = o4 + 4m
    float accr[8][4] = {}, acci[8][4] = {};
    const int wb = g * 32768 + k;         // + i*1024 + o*32
    for (int i = 0; i < 32; ++i) {
        const float4 xr4 = *(const float4*)(XrL + i * 256 + wq * 4);
        const float4 xi4 = *(const float4*)(XiL + i * 256 + wq * 4);
        const int wbi = wb + i * 1024;
        #pragma unroll
        for (int m = 0; m < 8; ++m) {
            const int o = o4 + 4 * m;
            const float wr = w1r[wbi + o * 32];
            const float wi = w1i[wbi + o * 32];
            accr[m][0] += xr4.x * wr - xi4.x * wi;  acci[m][0] += xr4.x * wi + xi4.x * wr;
            accr[m][1] += xr4.y * wr - xi4.y * wi;  acci[m][1] += xr4.y * wi + xi4.y * wr;
            accr[m][2] += xr4.z * wr - xi4.z * wi;  acci[m][2] += xr4.z * wi + xi4.z * wr;
            accr[m][3] += xr4.w * wr - xi4.w * wi;  acci[m][3] += xr4.w * wi + xi4.w * wr;
        }
    }
    const float sck = (k == 0) ? (1.f / 256.f) : (2.f / 256.f);
    const size_t ob = (((size_t)(b * 2 + g) * 32) * 32 + k) * 256 + wq * 4;  // + o*8192
    #pragma unroll
    for (int m = 0; m < 8; ++m) {
        const int o = o4 + 4 * m;
        *(float4*)(Yr + ob + (size_t)o * 8192) =
            make_float4(accr[m][0] * sck, accr[m][1] * sck, accr[m][2] * sck, accr[m][3] * sck);
        *(float4*)(Yi + ob + (size_t)o * 8192) =
            make_float4(acci[m][0] * sck, acci[m][1] * sck, acci[m][2] * sck, acci[m][3] * sck);
    }
}

// ---------------------------------------------------------------------------
// Stage H kernel 3: inverse truncated rDFT along H, mirror symmetry.
// block = (b,g,o); thread: wq = t&63 (w-quad), hs = t>>6; h = hs*32 + ch*4 + jj
// out[h]      = sumC - sumS
// out[256-h]  = sumC + sumS          (h >= 1)
// out[128]    = sum_k Yr'[k]*(-1)^k  (handled by hs==0, ch==0 threads)
// ---------------------------------------------------------------------------
__global__ __launch_bounds__(256) void h_inv(const float* __restrict__ Yr,
                                             const float* __restrict__ Yi,
                                             const float* __restrict__ tc,
                                             const float* __restrict__ ts,
                                             float* __restrict__ out) {
    __shared__ float YrL[32 * 256], YiL[32 * 256];
    const int bid = blockIdx.x;
    const int o = bid & 31, g = (bid >> 5) & 1, b = bid >> 6;
    const int t = threadIdx.x;

    const size_t sbase = ((size_t)((b * 2 + g) * 32 + o)) * 8192;   // + k*256 + w
    {
        const int wq = t & 63, k0 = t >> 6;
        #pragma unroll
        for (int r = 0; r < 8; ++r) {
            const int k = k0 + r * 4;
            *(float4*)(YrL + k * 256 + wq * 4) =
                *(const float4*)(Yr + sbase + (size_t)k * 256 + wq * 4);
            *(float4*)(YiL + k * 256 + wq * 4) =
                *(const float4*)(Yi + sbase + (size_t)k * 256 + wq * 4);
        }
    }
    __syncthreads();

    const int wq = t & 63, hs = t >> 6;
    float* outp = out + ((size_t)(b * 64 + g * 32 + o)) * 65536 + wq * 4;

    for (int ch = 0; ch < 8; ++ch) {
        const int h0 = hs * 32 + ch * 4;                   // 0..124, b128-aligned
        float4 sc0 = {0,0,0,0}, sc1 = {0,0,0,0}, sc2 = {0,0,0,0}, sc3 = {0,0,0,0};
        float4 ss0 = {0,0,0,0}, ss1 = {0,0,0,0}, ss2 = {0,0,0,0}, ss3 = {0,0,0,0};
        for (int k = 0; k < 32; ++k) {
            const float4 yr4 = *(const float4*)(YrL + k * 256 + wq * 4);
            const float4 yi4 = *(const float4*)(YiL + k * 256 + wq * 4);
            const float4 c4  = *(const float4*)(tc + (size_t)k * 256 + h0);  // broadcast
            const float4 s4  = *(const float4*)(ts + (size_t)k * 256 + h0);
            sc0.x += yr4.x * c4.x; sc0.y += yr4.y * c4.x; sc0.z += yr4.z * c4.x; sc0.w += yr4.w * c4.x;
            ss0.x += yi4.x * s4.x; ss0.y += yi4.y * s4.x; ss0.z += yi4.z * s4.x; ss0.w += yi4.w * s4.x;
            sc1.x += yr4.x * c4.y; sc1.y += yr4.y * c4.y; sc1.z += yr4.z * c4.y; sc1.w += yr4.w * c4.y;
            ss1.x += yi4.x * s4.y; ss1.y += yi4.y * s4.y; ss1.z += yi4.z * s4.y; ss1.w += yi4.w * s4.y;
            sc2.x += yr4.x * c4.z; sc2.y += yr4.y * c4.z; sc2.z += yr4.z * c4.z; sc2.w += yr4.w * c4.z;
            ss2.x += yi4.x * s4.z; ss2.y += yi4.y * s4.z; ss2.z += yi4.z * s4.z; ss2.w += yi4.w * s4.z;
            sc3.x += yr4.x * c4.w; sc3.y += yr4.y * c4.w; sc3.z += yr4.z * c4.w; sc3.w += yr4.w * c4.w;
            ss3.x += yi4.x * s4.w; ss3.y += yi4.y * s4.w; ss3.z += yi4.z * s4.w; ss3.w += yi4.w * s4.w;
        }
        #pragma unroll
        for (int jj = 0; jj < 4; ++jj) {
            const int h = h0 + jj;
            const float4 sc = jj == 0 ? sc0 : jj == 1 ? sc1 : jj == 2 ? sc2 : sc3;
            const float4 ss = jj == 0 ? ss0 : jj == 1 ? ss1 : jj == 2 ? ss2 : ss3;
            *(float4*)(outp + (size_t)h * 256) =
                make_float4(sc.x - ss.x, sc.y - ss.y, sc.z - ss.z, sc.w - ss.w);
            if (h > 0) {
                *(float4*)(outp + (size_t)(256 - h) * 256) =
                    make_float4(sc.x + ss.x, sc.y + ss.y, sc.z + ss.z, sc.w + ss.w);
            }
        }
        if (hs == 0 && ch == 0) {                          // h = 128 (Nyquist row)
            float4 a128 = {0,0,0,0};
            for (int k = 0; k < 32; ++k) {
                const float4 yr4 = *(const float4*)(YrL + k * 256 + wq * 4);
                const float sgn = (k & 1) ? -1.f : 1.f;
                a128.x += sgn * yr4.x; a128.y += sgn * yr4.y;
                a128.z += sgn * yr4.z; a128.w += sgn * yr4.w;
            }
            *(float4*)(outp + (size_t)128 * 256) = a128;
        }
    }
}

// ---------------------------------------------------------------------------
extern "C" void kernel_launch(void* const* d_in, const int* in_sizes, int n_in,
                              void* d_out, int out_size, void* d_ws, size_t ws_size,
                              hipStream_t stream) {
    const float* x   = (const float*)d_in[0];
    const float* w1r = (const float*)d_in[1];
    const float* w1i = (const float*)d_in[2];
    const float* w2r = (const float*)d_in[3];
    const float* w2i = (const float*)d_in[4];
    float* out = (float*)d_out;
    float* ws  = (float*)d_ws;

    float* tc = ws;                   // 16384 floats
    float* ts = ws + 16384;           // 16384 floats
    float* Xr = ws + 32768;           // 4,194,304 floats each
    float* Xi = Xr + 4194304;
    float* Yr = Xi + 4194304;
    float* Yi = Yr + 4194304;

    init_tab<<<64, 256, 0, stream>>>(tc, ts);
    stage_w<<<4096, 256, 0, stream>>>(x, w2r, w2i, tc, ts, out);   // y1 -> d_out (scratch)
    h_dft<<<512, 512, 0, stream>>>(out, tc, ts, Xr, Xi);
    h_mix<<<512, 256, 0, stream>>>(Xr, Xi, w1r, w1i, Yr, Yi);
    h_inv<<<512, 256, 0, stream>>>(Yr, Yi, tc, ts, out);
}

// Round 4
// 282.295 us; speedup vs baseline: 2.3859x; 1.3848x over previous
//
#include <hip/hip_runtime.h>
#include <math.h>

// x: [8][64][256][256] f32 ; w1/w2: [2][32][32][32] f32 (re,im separate)
#define PI2_256 0.0245436926061702596754894014318f  // 2*pi/256

// ---------------------------------------------------------------------------
// trig tables tc[k][n] = cos(2 pi k n/256), ts = sin(...), k<32, n<256
// ---------------------------------------------------------------------------
__global__ __launch_bounds__(256) void init_tab(float* __restrict__ tc, float* __restrict__ ts) {
    int idx = blockIdx.x * 256 + threadIdx.x;   // 0..16383
    int k = idx >> 8, n = idx & 255;
    int m = (k * n) & 255;
    float s, c;
    sincosf(PI2_256 * (float)m, &s, &c);
    tc[idx] = c;
    ts[idx] = s;
}

// ---------------------------------------------------------------------------
// Stage W (fused): block = (b,g,xrow). folded DFT(W) -> mix -> folded iDFT(W)
// ---------------------------------------------------------------------------
__global__ __launch_bounds__(256) void stage_w(const float* __restrict__ x,
                                               const float* __restrict__ w2r,
                                               const float* __restrict__ w2i,
                                               const float* __restrict__ tc,
                                               const float* __restrict__ ts,
                                               float* __restrict__ y1) {
    __shared__ float tile[32 * 256];                       // 32 KB; folded in-place
    __shared__ float XrL[32 * 36], XiL[32 * 36];           // [i][k], pad 36
    __shared__ float YrL[32 * 36], YiL[32 * 36];           // [o][k], pad 36

    const int bid  = blockIdx.x;
    const int xrow = bid & 255;
    const int g    = (bid >> 8) & 1;
    const int b    = bid >> 9;
    const int t    = threadIdx.x;

    const size_t chan0 = (size_t)(b * 64 + g * 32);
    const size_t base  = (chan0 * 256 + xrow) * 256;       // + i*65536 + w

    // ---- stage input tile (coalesced float4) ----
    {
        const int wq = t & 63, i0 = t >> 6;
        #pragma unroll
        for (int r = 0; r < 8; ++r) {
            const int i = i0 + r * 4;
            *(float4*)(tile + i * 256 + wq * 4) =
                *(const float4*)(x + base + (size_t)i * 65536 + wq * 4);
        }
    }
    __syncthreads();

    // ---- fold prepass (in place): tile[i][0..127] = ye (ye[0]=2*x0),
    //      tile[i][128] = x128, tile[i][129..255] = yo[h]=x[h]-x[256-h] ----
    {
        const int hq = t & 31, i0 = t >> 5;                // i = i0 + 8r
        const int h0 = hq * 4;
        float4 a4[4]; float m0[4], m1[4], m2[4], m3[4]; float x128v[4];
        #pragma unroll
        for (int r = 0; r < 4; ++r) {
            const float* row = tile + (i0 + r * 8) * 256;
            a4[r] = *(const float4*)(row + h0);
            m0[r] = row[(256 - (h0 + 0)) & 255];
            m1[r] = row[256 - (h0 + 1)];
            m2[r] = row[256 - (h0 + 2)];
            m3[r] = row[256 - (h0 + 3)];
            x128v[r] = row[128];                           // only used when hq==0
        }
        __syncthreads();
        #pragma unroll
        for (int r = 0; r < 4; ++r) {
            float* row = tile + (i0 + r * 8) * 256;
            float4 ye = make_float4(a4[r].x + m0[r], a4[r].y + m1[r],
                                    a4[r].z + m2[r], a4[r].w + m3[r]);
            float4 yo = make_float4(a4[r].x - m0[r], a4[r].y - m1[r],
                                    a4[r].z - m2[r], a4[r].w - m3[r]);
            if (hq == 0) yo.x = x128v[r];                  // stash x128 in yo[0] slot (s0=0)
            *(float4*)(row + h0)       = ye;
            *(float4*)(row + 128 + h0) = yo;
        }
    }
    __syncthreads();

    // ---- phase A: folded truncated DFT along W, Chebyshev trig (2 FMA/h) ----
    // Xr[k] = (-1)^k*x128 - x0 + sum_{h=0..127} ye[h] cos(kh')
    // Xi[k] = -sum_{h=1..127} yo[h] sin(kh')
    {
        const int k = t & 31, i4 = t >> 5;
        float sd, cd; sincosf(PI2_256 * (float)k, &sd, &cd);
        const float t2 = 2.f * cd;
        float cA = 1.f, sA = 0.f;                          // phasor at h
        float cB = cd,  sB = -sd;                          // phasor at h-1
        const float* r0 = tile + i4 * 256;
        const float* r1 = r0 + 8 * 256;
        const float* r2 = r0 + 16 * 256;
        const float* r3 = r0 + 24 * 256;
        const float x0_0 = r0[0] * 0.5f, x128_0 = r0[128];
        const float x0_1 = r1[0] * 0.5f, x128_1 = r1[128];
        const float x0_2 = r2[0] * 0.5f, x128_2 = r2[128];
        const float x0_3 = r3[0] * 0.5f, x128_3 = r3[128];
        const float sgn = (k & 1) ? -1.f : 1.f;
        float xr0 = sgn * x128_0 - x0_0, xi0 = 0.f;
        float xr1 = sgn * x128_1 - x0_1, xi1 = 0.f;
        float xr2 = sgn * x128_2 - x0_2, xi2 = 0.f;
        float xr3 = sgn * x128_3 - x0_3, xi3 = 0.f;
        for (int hq = 0; hq < 32; ++hq) {
            const float4 yeA = *(const float4*)(r0 + hq * 4);
            const float4 yoA = *(const float4*)(r0 + 128 + hq * 4);
            const float4 yeB = *(const float4*)(r1 + hq * 4);
            const float4 yoB = *(const float4*)(r1 + 128 + hq * 4);
            const float4 yeC = *(const float4*)(r2 + hq * 4);
            const float4 yoC = *(const float4*)(r2 + 128 + hq * 4);
            const float4 yeD = *(const float4*)(r3 + hq * 4);
            const float4 yoD = *(const float4*)(r3 + 128 + hq * 4);
            #pragma unroll
            for (int j = 0; j < 4; ++j) {
                const float c = cA, s = sA;
                xr0 += (&yeA.x)[j] * c;  xi0 -= (&yoA.x)[j] * s;
                xr1 += (&yeB.x)[j] * c;  xi1 -= (&yoB.x)[j] * s;
                xr2 += (&yeC.x)[j] * c;  xi2 -= (&yoC.x)[j] * s;
                xr3 += (&yeD.x)[j] * c;  xi3 -= (&yoD.x)[j] * s;
                const float cn = t2 * cA - cB; cB = cA; cA = cn;   // Chebyshev step
                const float sn = t2 * sA - sB; sB = sA; sA = sn;
            }
        }
        XrL[(i4     ) * 36 + k] = xr0;  XiL[(i4     ) * 36 + k] = xi0;
        XrL[(i4 +  8) * 36 + k] = xr1;  XiL[(i4 +  8) * 36 + k] = xi1;
        XrL[(i4 + 16) * 36 + k] = xr2;  XiL[(i4 + 16) * 36 + k] = xi2;
        XrL[(i4 + 24) * 36 + k] = xr3;  XiL[(i4 + 24) * 36 + k] = xi3;
    }
    __syncthreads();

    // ---- phase B: channel mix, k-quad per thread; ortho scale folded ----
    {
        const int kq = t & 7, o = t >> 3;
        const int k4 = kq * 4;
        float4 ar = {0,0,0,0}, ai = {0,0,0,0};
        const float* wrb = w2r + (size_t)g * 32768 + o * 32 + k4;   // + i*1024
        const float* wib = w2i + (size_t)g * 32768 + o * 32 + k4;
        for (int i = 0; i < 32; ++i) {
            const float4 xr = *(const float4*)(XrL + i * 36 + k4);
            const float4 xi = *(const float4*)(XiL + i * 36 + k4);
            const float4 wr = *(const float4*)(wrb + i * 1024);
            const float4 wi = *(const float4*)(wib + i * 1024);
            ar.x += xr.x * wr.x - xi.x * wi.x;  ai.x += xr.x * wi.x + xi.x * wr.x;
            ar.y += xr.y * wr.y - xi.y * wi.y;  ai.y += xr.y * wi.y + xi.y * wr.y;
            ar.z += xr.z * wr.z - xi.z * wi.z;  ai.z += xr.z * wi.z + xi.z * wr.z;
            ar.w += xr.w * wr.w - xi.w * wi.w;  ai.w += xr.w * wi.w + xi.w * wr.w;
        }
        const float s2 = 2.f / 256.f, s1 = 1.f / 256.f;
        const float s0 = (k4 == 0) ? s1 : s2;
        *(float4*)(YrL + o * 36 + k4) = make_float4(ar.x * s0, ar.y * s2, ar.z * s2, ar.w * s2);
        *(float4*)(YiL + o * 36 + k4) = make_float4(ai.x * s0, ai.y * s2, ai.z * s2, ai.w * s2);
    }
    __syncthreads();

    // ---- phase C: folded inverse. sumC/sumS for w in [0,128); emit w and 256-w ----
    {
        const int wq = t & 31, oh = t >> 5;                // o = oh + 8m
        const int w0 = wq * 4;
        float sC[4][4] = {{0}}, sS[4][4] = {{0}};
        for (int k = 0; k < 32; ++k) {
            const float4 c4 = *(const float4*)(tc + (size_t)k * 256 + w0);
            const float4 s4 = *(const float4*)(ts + (size_t)k * 256 + w0);
            #pragma unroll
            for (int m = 0; m < 4; ++m) {
                const int o = oh + 8 * m;
                const float yr = YrL[o * 36 + k];
                const float yi = YiL[o * 36 + k];
                sC[m][0] += yr * c4.x; sC[m][1] += yr * c4.y;
                sC[m][2] += yr * c4.z; sC[m][3] += yr * c4.w;
                sS[m][0] += yi * s4.x; sS[m][1] += yi * s4.y;
                sS[m][2] += yi * s4.z; sS[m][3] += yi * s4.w;
            }
        }
        #pragma unroll
        for (int m = 0; m < 4; ++m) {
            const int o = oh + 8 * m;
            float* op = y1 + (chan0 + o) * 65536 + (size_t)xrow * 256;
            *(float4*)(op + w0) = make_float4(sC[m][0] - sS[m][0], sC[m][1] - sS[m][1],
                                              sC[m][2] - sS[m][2], sC[m][3] - sS[m][3]);
            #pragma unroll
            for (int j = 0; j < 4; ++j) {
                const int w = w0 + j;
                if (w >= 1) op[256 - w] = sC[m][j] + sS[m][j];
            }
        }
        if (wq == 0) {                                     // w = 128 (Nyquist column)
            #pragma unroll
            for (int m = 0; m < 4; ++m) {
                const int o = oh + 8 * m;
                float ny = 0.f;
                for (int k = 0; k < 32; ++k) {
                    const float yr = YrL[o * 36 + k];
                    ny += (k & 1) ? -yr : yr;
                }
                y1[(chan0 + o) * 65536 + (size_t)xrow * 256 + 128] = ny;
            }
        }
    }
}

// ---------------------------------------------------------------------------
// Stage H kernel 1: truncated DFT along H with even/odd mirror symmetry.
// ---------------------------------------------------------------------------
__global__ __launch_bounds__(512) void h_dft(const float* __restrict__ y1,
                                             const float* __restrict__ tc,
                                             const float* __restrict__ ts,
                                             float* __restrict__ Xr,
                                             float* __restrict__ Xi) {
    __shared__ float TcL[32 * 128], TsL[32 * 128];         // half tables
    const int t = threadIdx.x;
    #pragma unroll
    for (int rep = 0; rep < 2; ++rep) {
        const int q = t + rep * 512;                       // quad id 0..1023
        const int k = q >> 5, hq = q & 31;
        *(float4*)(TcL + k * 128 + hq * 4) = *(const float4*)(tc + (size_t)k * 256 + hq * 4);
        *(float4*)(TsL + k * 128 + hq * 4) = *(const float4*)(ts + (size_t)k * 256 + hq * 4);
    }
    __syncthreads();

    const int bid = blockIdx.x;
    const int i = bid & 31, g = (bid >> 5) & 1, b = bid >> 6;
    const int w = t & 255, kh = t >> 8;                    // k = kh*16 + r

    const float* src = y1 + (size_t)((b * 2 + g) * 32 + i) * 65536 + w;
    const float y0 = src[0], y128 = src[128 * 256];

    float xr[16], xi[16];
    #pragma unroll
    for (int r = 0; r < 16; ++r) {
        xr[r] = ((r & 1) ? -y128 : y128) - y0;
        xi[r] = 0.f;
    }

    const int kb = kh * 16;
    for (int hq = 0; hq < 32; ++hq) {
        float ye[4], yo[4];
        #pragma unroll
        for (int j = 0; j < 4; ++j) {
            const int h = hq * 4 + j;
            const float a = src[(size_t)h * 256];
            const float m = src[(size_t)((256 - h) & 255) * 256];
            ye[j] = a + m;
            yo[j] = a - m;
        }
        #pragma unroll
        for (int r = 0; r < 16; ++r) {
            const float4 c4 = *(const float4*)(TcL + (kb + r) * 128 + hq * 4);
            const float4 s4 = *(const float4*)(TsL + (kb + r) * 128 + hq * 4);
            xr[r] += ye[0] * c4.x + ye[1] * c4.y + ye[2] * c4.z + ye[3] * c4.w;
            xi[r] -= yo[0] * s4.x + yo[1] * s4.y + yo[2] * s4.z + yo[3] * s4.w;
        }
    }
    const size_t obase = (size_t)((b * 2 + g) * 32 + i) * 8192 + w;   // + k*256
    #pragma unroll
    for (int r = 0; r < 16; ++r) {
        Xr[obase + (size_t)(kb + r) * 256] = xr[r];
        Xi[obase + (size_t)(kb + r) * 256] = xi[r];
    }
}

// ---------------------------------------------------------------------------
// Stage H kernel 2: channel mix per (b,g,k); ortho scale folded here.
// ---------------------------------------------------------------------------
__global__ __launch_bounds__(256) void h_mix(const float* __restrict__ Xr,
                                             const float* __restrict__ Xi,
                                             const float* __restrict__ w1r,
                                             const float* __restrict__ w1i,
                                             float* __restrict__ Yr,
                                             float* __restrict__ Yi) {
    __shared__ float XrL[32 * 256], XiL[32 * 256];
    const int bid = blockIdx.x;
    const int k = bid & 31, g = (bid >> 5) & 1, b = bid >> 6;
    const int t = threadIdx.x;

    const size_t sbase = (((size_t)(b * 2 + g) * 32) * 32 + k) * 256;  // + i*8192 + w
    {
        const int wq = t & 63, i0 = t >> 6;
        #pragma unroll
        for (int r = 0; r < 8; ++r) {
            const int i = i0 + r * 4;
            *(float4*)(XrL + i * 256 + wq * 4) =
                *(const float4*)(Xr + sbase + (size_t)i * 8192 + wq * 4);
            *(float4*)(XiL + i * 256 + wq * 4) =
                *(const float4*)(Xi + sbase + (size_t)i * 8192 + wq * 4);
        }
    }
    __syncthreads();

    const int wq = t & 63, o4 = t >> 6;   // o = o4 + 4m
    float accr[8][4] = {{0}}, acci[8][4] = {{0}};
    const int wb = g * 32768 + k;         // + i*1024 + o*32
    for (int i = 0; i < 32; ++i) {
        const float4 xr4 = *(const float4*)(XrL + i * 256 + wq * 4);
        const float4 xi4 = *(const float4*)(XiL + i * 256 + wq * 4);
        const int wbi = wb + i * 1024;
        #pragma unroll
        for (int m = 0; m < 8; ++m) {
            const int o = o4 + 4 * m;
            const float wr = w1r[wbi + o * 32];
            const float wi = w1i[wbi + o * 32];
            accr[m][0] += xr4.x * wr - xi4.x * wi;  acci[m][0] += xr4.x * wi + xi4.x * wr;
            accr[m][1] += xr4.y * wr - xi4.y * wi;  acci[m][1] += xr4.y * wi + xi4.y * wr;
            accr[m][2] += xr4.z * wr - xi4.z * wi;  acci[m][2] += xr4.z * wi + xi4.z * wr;
            accr[m][3] += xr4.w * wr - xi4.w * wi;  acci[m][3] += xr4.w * wi + xi4.w * wr;
        }
    }
    const float sck = (k == 0) ? (1.f / 256.f) : (2.f / 256.f);
    const size_t ob = (((size_t)(b * 2 + g) * 32) * 32 + k) * 256 + wq * 4;  // + o*8192
    #pragma unroll
    for (int m = 0; m < 8; ++m) {
        const int o = o4 + 4 * m;
        *(float4*)(Yr + ob + (size_t)o * 8192) =
            make_float4(accr[m][0] * sck, accr[m][1] * sck, accr[m][2] * sck, accr[m][3] * sck);
        *(float4*)(Yi + ob + (size_t)o * 8192) =
            make_float4(acci[m][0] * sck, acci[m][1] * sck, acci[m][2] * sck, acci[m][3] * sck);
    }
}

// ---------------------------------------------------------------------------
// Stage H kernel 3: inverse truncated rDFT along H, mirror symmetry.
// ---------------------------------------------------------------------------
__global__ __launch_bounds__(256) void h_inv(const float* __restrict__ Yr,
                                             const float* __restrict__ Yi,
                                             const float* __restrict__ tc,
                                             const float* __restrict__ ts,
                                             float* __restrict__ out) {
    __shared__ float YrL[32 * 256], YiL[32 * 256];
    const int bid = blockIdx.x;
    const int o = bid & 31, g = (bid >> 5) & 1, b = bid >> 6;
    const int t = threadIdx.x;

    const size_t sbase = ((size_t)((b * 2 + g) * 32 + o)) * 8192;   // + k*256 + w
    {
        const int wq = t & 63, k0 = t >> 6;
        #pragma unroll
        for (int r = 0; r < 8; ++r) {
            const int k = k0 + r * 4;
            *(float4*)(YrL + k * 256 + wq * 4) =
                *(const float4*)(Yr + sbase + (size_t)k * 256 + wq * 4);
            *(float4*)(YiL + k * 256 + wq * 4) =
                *(const float4*)(Yi + sbase + (size_t)k * 256 + wq * 4);
        }
    }
    __syncthreads();

    const int wq = t & 63, hs = t >> 6;
    float* outp = out + ((size_t)(b * 64 + g * 32 + o)) * 65536 + wq * 4;

    for (int ch = 0; ch < 8; ++ch) {
        const int h0 = hs * 32 + ch * 4;                   // 0..124
        float4 sc0 = {0,0,0,0}, sc1 = {0,0,0,0}, sc2 = {0,0,0,0}, sc3 = {0,0,0,0};
        float4 ss0 = {0,0,0,0}, ss1 = {0,0,0,0}, ss2 = {0,0,0,0}, ss3 = {0,0,0,0};
        for (int k = 0; k < 32; ++k) {
            const float4 yr4 = *(const float4*)(YrL + k * 256 + wq * 4);
            const float4 yi4 = *(const float4*)(YiL + k * 256 + wq * 4);
            const float4 c4  = *(const float4*)(tc + (size_t)k * 256 + h0);
            const float4 s4  = *(const float4*)(ts + (size_t)k * 256 + h0);
            sc0.x += yr4.x * c4.x; sc0.y += yr4.y * c4.x; sc0.z += yr4.z * c4.x; sc0.w += yr4.w * c4.x;
            ss0.x += yi4.x * s4.x; ss0.y += yi4.y * s4.x; ss0.z += yi4.z * s4.x; ss0.w += yi4.w * s4.x;
            sc1.x += yr4.x * c4.y; sc1.y += yr4.y * c4.y; sc1.z += yr4.z * c4.y; sc1.w += yr4.w * c4.y;
            ss1.x += yi4.x * s4.y; ss1.y += yi4.y * s4.y; ss1.z += yi4.z * s4.y; ss1.w += yi4.w * s4.y;
            sc2.x += yr4.x * c4.z; sc2.y += yr4.y * c4.z; sc2.z += yr4.z * c4.z; sc2.w += yr4.w * c4.z;
            ss2.x += yi4.x * s4.z; ss2.y += yi4.y * s4.z; ss2.z += yi4.z * s4.z; ss2.w += yi4.w * s4.z;
            sc3.x += yr4.x * c4.w; sc3.y += yr4.y * c4.w; sc3.z += yr4.z * c4.w; sc3.w += yr4.w * c4.w;
            ss3.x += yi4.x * s4.w; ss3.y += yi4.y * s4.w; ss3.z += yi4.z * s4.w; ss3.w += yi4.w * s4.w;
        }
        #pragma unroll
        for (int jj = 0; jj < 4; ++jj) {
            const int h = h0 + jj;
            const float4 sc = jj == 0 ? sc0 : jj == 1 ? sc1 : jj == 2 ? sc2 : sc3;
            const float4 ss = jj == 0 ? ss0 : jj == 1 ? ss1 : jj == 2 ? ss2 : ss3;
            *(float4*)(outp + (size_t)h * 256) =
                make_float4(sc.x - ss.x, sc.y - ss.y, sc.z - ss.z, sc.w - ss.w);
            if (h > 0) {
                *(float4*)(outp + (size_t)(256 - h) * 256) =
                    make_float4(sc.x + ss.x, sc.y + ss.y, sc.z + ss.z, sc.w + ss.w);
            }
        }
        if (hs == 0 && ch == 0) {                          // h = 128 (Nyquist row)
            float4 a128 = {0,0,0,0};
            for (int k = 0; k < 32; ++k) {
                const float4 yr4 = *(const float4*)(YrL + k * 256 + wq * 4);
                const float sgn = (k & 1) ? -1.f : 1.f;
                a128.x += sgn * yr4.x; a128.y += sgn * yr4.y;
                a128.z += sgn * yr4.z; a128.w += sgn * yr4.w;
            }
            *(float4*)(outp + (size_t)128 * 256) = a128;
        }
    }
}

// ---------------------------------------------------------------------------
extern "C" void kernel_launch(void* const* d_in, const int* in_sizes, int n_in,
                              void* d_out, int out_size, void* d_ws, size_t ws_size,
                              hipStream_t stream) {
    const float* x   = (const float*)d_in[0];
    const float* w1r = (const float*)d_in[1];
    const float* w1i = (const float*)d_in[2];
    const float* w2r = (const float*)d_in[3];
    const float* w2i = (const float*)d_in[4];
    float* out = (float*)d_out;
    float* ws  = (float*)d_ws;

    float* tc = ws;                   // 16384 floats
    float* ts = ws + 16384;           // 16384 floats
    float* Xr = ws + 32768;           // 4,194,304 floats each
    float* Xi = Xr + 4194304;
    float* Yr = Xi + 4194304;
    float* Yi = Yr + 4194304;

    init_tab<<<64, 256, 0, stream>>>(tc, ts);
    stage_w<<<4096, 256, 0, stream>>>(x, w2r, w2i, tc, ts, out);   // y1 -> d_out (scratch)
    h_dft<<<512, 512, 0, stream>>>(out, tc, ts, Xr, Xi);
    h_mix<<<512, 256, 0, stream>>>(Xr, Xi, w1r, w1i, Yr, Yi);
    h_inv<<<512, 256, 0, stream>>>(Yr, Yi, tc, ts, out);
}

// Round 5
// 265.839 us; speedup vs baseline: 2.5335x; 1.0619x over previous
//
#include <hip/hip_runtime.h>
#include <math.h>

// x: [8][64][256][256] f32 ; w1/w2: [2][32][32][32] f32 (re,im separate)
// Pipeline (all linear ops commute across tensor factors):
//   K1: DFT_W (folded) + mixW  -> Yw[b,g,o,h,64]   (64 = 32 Re | 32 Im w-modes)
//   K2: DFT_H (folded)         -> Z [bg,kh,o,128]  (128 = 64 Re_h | 64 Im_h slots)
//   K3: mixH                   -> Z2[bg,o,kh,128]
//   K45: IDFT_H (mirror) + IDFT_W (mirror) fused -> out
#define PI2_256 0.0245436926061702596754894014318f  // 2*pi/256

// ---------------------------------------------------------------------------
__global__ __launch_bounds__(256) void init_tab(float* __restrict__ tc, float* __restrict__ ts) {
    int idx = blockIdx.x * 256 + threadIdx.x;   // 0..8191
    int k = idx >> 8, n = idx & 255;            // k < 32
    int m = (k * n) & 255;
    float s, c;
    sincosf(PI2_256 * (float)m, &s, &c);
    tc[idx] = c;
    ts[idx] = s;
}

// ---------------------------------------------------------------------------
// K1: per block = (b,g,xrow). folded DFT_W -> mixW (scale folded) -> global
// ---------------------------------------------------------------------------
__global__ __launch_bounds__(256) void w_fwd(const float* __restrict__ x,
                                             const float* __restrict__ w2r,
                                             const float* __restrict__ w2i,
                                             float* __restrict__ Yw) {
    __shared__ float tile[32 * 256];               // 32 KB; folded in-place
    __shared__ float XrL[32 * 36], XiL[32 * 36];   // [i][k], pad 36

    const int bid  = blockIdx.x;
    const int xrow = bid & 255;
    const int g    = (bid >> 8) & 1;
    const int b    = bid >> 9;
    const int t    = threadIdx.x;

    const size_t chan0 = (size_t)(b * 64 + g * 32);
    const size_t base  = (chan0 * 256 + xrow) * 256;       // + i*65536 + w

    // ---- stage input tile (coalesced float4) ----
    {
        const int wq = t & 63, i0 = t >> 6;
        #pragma unroll
        for (int r = 0; r < 8; ++r) {
            const int i = i0 + r * 4;
            *(float4*)(tile + i * 256 + wq * 4) =
                *(const float4*)(x + base + (size_t)i * 65536 + wq * 4);
        }
    }
    __syncthreads();

    // ---- fold prepass (in place): tile[i][0..127] = ye (ye[0]=2*x0),
    //      tile[i][128] = x128, tile[i][129..255] = yo ----
    {
        const int hq = t & 31, i0 = t >> 5;
        const int h0 = hq * 4;
        float4 a4[4]; float m0[4], m1[4], m2[4], m3[4]; float x128v[4];
        #pragma unroll
        for (int r = 0; r < 4; ++r) {
            const float* row = tile + (i0 + r * 8) * 256;
            a4[r] = *(const float4*)(row + h0);
            m0[r] = row[(256 - (h0 + 0)) & 255];
            m1[r] = row[256 - (h0 + 1)];
            m2[r] = row[256 - (h0 + 2)];
            m3[r] = row[256 - (h0 + 3)];
            x128v[r] = row[128];
        }
        __syncthreads();
        #pragma unroll
        for (int r = 0; r < 4; ++r) {
            float* row = tile + (i0 + r * 8) * 256;
            float4 ye = make_float4(a4[r].x + m0[r], a4[r].y + m1[r],
                                    a4[r].z + m2[r], a4[r].w + m3[r]);
            float4 yo = make_float4(a4[r].x - m0[r], a4[r].y - m1[r],
                                    a4[r].z - m2[r], a4[r].w - m3[r]);
            if (hq == 0) yo.x = x128v[r];                  // stash x128 (s0=0 slot)
            *(float4*)(row + h0)       = ye;
            *(float4*)(row + 128 + h0) = yo;
        }
    }
    __syncthreads();

    // ---- phase A: folded truncated DFT along W, Chebyshev trig ----
    {
        const int k = t & 31, i4 = t >> 5;
        float sd, cd; sincosf(PI2_256 * (float)k, &sd, &cd);
        const float t2 = 2.f * cd;
        float cA = 1.f, sA = 0.f;                          // phasor at h
        float cB = cd,  sB = -sd;                          // phasor at h-1
        const float* r0 = tile + i4 * 256;
        const float* r1 = r0 + 8 * 256;
        const float* r2 = r0 + 16 * 256;
        const float* r3 = r0 + 24 * 256;
        const float x0_0 = r0[0] * 0.5f, x128_0 = r0[128];
        const float x0_1 = r1[0] * 0.5f, x128_1 = r1[128];
        const float x0_2 = r2[0] * 0.5f, x128_2 = r2[128];
        const float x0_3 = r3[0] * 0.5f, x128_3 = r3[128];
        const float sgn = (k & 1) ? -1.f : 1.f;
        float xr0 = sgn * x128_0 - x0_0, xi0 = 0.f;
        float xr1 = sgn * x128_1 - x0_1, xi1 = 0.f;
        float xr2 = sgn * x128_2 - x0_2, xi2 = 0.f;
        float xr3 = sgn * x128_3 - x0_3, xi3 = 0.f;
        for (int hq = 0; hq < 32; ++hq) {
            const float4 yeA = *(const float4*)(r0 + hq * 4);
            const float4 yoA = *(const float4*)(r0 + 128 + hq * 4);
            const float4 yeB = *(const float4*)(r1 + hq * 4);
            const float4 yoB = *(const float4*)(r1 + 128 + hq * 4);
            const float4 yeC = *(const float4*)(r2 + hq * 4);
            const float4 yoC = *(const float4*)(r2 + 128 + hq * 4);
            const float4 yeD = *(const float4*)(r3 + hq * 4);
            const float4 yoD = *(const float4*)(r3 + 128 + hq * 4);
            #pragma unroll
            for (int j = 0; j < 4; ++j) {
                const float c = cA, s = sA;
                xr0 += (&yeA.x)[j] * c;  xi0 -= (&yoA.x)[j] * s;
                xr1 += (&yeB.x)[j] * c;  xi1 -= (&yoB.x)[j] * s;
                xr2 += (&yeC.x)[j] * c;  xi2 -= (&yoC.x)[j] * s;
                xr3 += (&yeD.x)[j] * c;  xi3 -= (&yoD.x)[j] * s;
                const float cn = t2 * cA - cB; cB = cA; cA = cn;
                const float sn = t2 * sA - sB; sB = sA; sA = sn;
            }
        }
        XrL[(i4     ) * 36 + k] = xr0;  XiL[(i4     ) * 36 + k] = xi0;
        XrL[(i4 +  8) * 36 + k] = xr1;  XiL[(i4 +  8) * 36 + k] = xi1;
        XrL[(i4 + 16) * 36 + k] = xr2;  XiL[(i4 + 16) * 36 + k] = xi2;
        XrL[(i4 + 24) * 36 + k] = xr3;  XiL[(i4 + 24) * 36 + k] = xi3;
    }
    __syncthreads();

    // ---- phase B: mixW, scale folded; write 64-real spectral row to global ----
    {
        const int kq = t & 7, o = t >> 3;
        const int k4 = kq * 4;
        float4 ar = {0,0,0,0}, ai = {0,0,0,0};
        const float* wrb = w2r + (size_t)g * 32768 + o * 32 + k4;   // + i*1024
        const float* wib = w2i + (size_t)g * 32768 + o * 32 + k4;
        for (int i = 0; i < 32; ++i) {
            const float4 xr = *(const float4*)(XrL + i * 36 + k4);
            const float4 xi = *(const float4*)(XiL + i * 36 + k4);
            const float4 wr = *(const float4*)(wrb + i * 1024);
            const float4 wi = *(const float4*)(wib + i * 1024);
            ar.x += xr.x * wr.x - xi.x * wi.x;  ai.x += xr.x * wi.x + xi.x * wr.x;
            ar.y += xr.y * wr.y - xi.y * wi.y;  ai.y += xr.y * wi.y + xi.y * wr.y;
            ar.z += xr.z * wr.z - xi.z * wi.z;  ai.z += xr.z * wi.z + xi.z * wr.z;
            ar.w += xr.w * wr.w - xi.w * wi.w;  ai.w += xr.w * wi.w + xi.w * wr.w;
        }
        const float s2 = 2.f / 256.f, s1 = 1.f / 256.f;
        const float s0 = (k4 == 0) ? s1 : s2;
        float* dst = Yw + (size_t)((b * 2 + g) * 32 + o) * 16384 + (size_t)xrow * 64 + k4;
        *(float4*)(dst)      = make_float4(ar.x * s0, ar.y * s2, ar.z * s2, ar.w * s2);
        *(float4*)(dst + 32) = make_float4(ai.x * s0, ai.y * s2, ai.z * s2, ai.w * s2);
    }
}

// ---------------------------------------------------------------------------
// K2: folded DFT_H per (b,g,o). Input Yw[ch][h][64] (each slot a real h-signal)
// Z layout: [(bg*32 + kh)*32 + o][128]  (Re_h | Im_h)
// ---------------------------------------------------------------------------
__global__ __launch_bounds__(256) void h_fwd(const float* __restrict__ Yw,
                                             const float* __restrict__ tc,
                                             const float* __restrict__ ts,
                                             float* __restrict__ Z) {
    __shared__ float YL[256 * 64];   // 64 KB
    const int bid = blockIdx.x;      // (b*2+g)*32 + o
    const int t = threadIdx.x;
    {
        const float* src = Yw + (size_t)bid * 16384;
        #pragma unroll
        for (int r = 0; r < 16; ++r) {
            const int f = t + r * 256;
            *(float4*)(YL + f * 4) = *(const float4*)(src + f * 4);
        }
    }
    __syncthreads();

    const int s = t & 63, khg = t >> 6;     // kh = khg*8 + r
    const float y0 = YL[s], y128 = YL[128 * 64 + s];
    float xr[8], xi[8];
    #pragma unroll
    for (int r = 0; r < 8; ++r) {
        xr[r] = ((r & 1) ? -y128 : y128) - y0;
        xi[r] = 0.f;
    }
    const int kb = khg * 8;
    for (int hq = 0; hq < 32; ++hq) {
        float ye[4], yo[4];
        #pragma unroll
        for (int j = 0; j < 4; ++j) {
            const int h = hq * 4 + j;
            const float a = YL[h * 64 + s];
            const float m = YL[((256 - h) & 255) * 64 + s];
            ye[j] = a + m;  yo[j] = a - m;
        }
        #pragma unroll
        for (int r = 0; r < 8; ++r) {
            const float4 c4 = *(const float4*)(tc + (size_t)(kb + r) * 256 + hq * 4);
            const float4 s4 = *(const float4*)(ts + (size_t)(kb + r) * 256 + hq * 4);
            xr[r] += ye[0] * c4.x + ye[1] * c4.y + ye[2] * c4.z + ye[3] * c4.w;
            xi[r] -= yo[0] * s4.x + yo[1] * s4.y + yo[2] * s4.z + yo[3] * s4.w;
        }
    }
    const int o = bid & 31, bg = bid >> 5;
    #pragma unroll
    for (int r = 0; r < 8; ++r) {
        const size_t zi_ = (((size_t)bg * 32 + (kb + r)) * 32 + o) * 128 + s;
        Z[zi_]      = xr[r];
        Z[zi_ + 64] = xi[r];
    }
}

// ---------------------------------------------------------------------------
// K3: mixH per (b,g,kh); H-ortho scale folded. Z2: [(bg*32+o)*32+kh][128]
// ---------------------------------------------------------------------------
__global__ __launch_bounds__(256) void h_mix2(const float* __restrict__ Z,
                                              const float* __restrict__ w1r,
                                              const float* __restrict__ w1i,
                                              float* __restrict__ Z2) {
    __shared__ float ZL[32 * 128];          // [i][128] 16 KB
    __shared__ float WrL[1024], WiL[1024];  // [i*32+o] 8 KB
    const int bid = blockIdx.x;             // bg*32 + kh
    const int kh = bid & 31, bg = bid >> 5;
    const int g = bg & 1;
    const int t = threadIdx.x;
    {
        const float* src = Z + (size_t)bid * 4096;
        #pragma unroll
        for (int r = 0; r < 4; ++r) {
            const int f = t + r * 256;
            *(float4*)(ZL + f * 4) = *(const float4*)(src + f * 4);
        }
        #pragma unroll
        for (int r = 0; r < 4; ++r) {
            const int idx = t + r * 256;    // i = idx>>5, o = idx&31
            const int gidx = g * 32768 + (idx >> 5) * 1024 + (idx & 31) * 32 + kh;
            WrL[idx] = w1r[gidx];
            WiL[idx] = w1i[gidx];
        }
    }
    __syncthreads();

    const int s = t & 63, og = t >> 6;      // o = og*8 + m
    float accr[8], acci[8];
    #pragma unroll
    for (int m = 0; m < 8; ++m) { accr[m] = 0.f; acci[m] = 0.f; }
    for (int i = 0; i < 32; ++i) {
        const float zr = ZL[i * 128 + s];
        const float zi = ZL[i * 128 + 64 + s];
        #pragma unroll
        for (int m = 0; m < 8; ++m) {
            const int o = og * 8 + m;
            const float wr = WrL[i * 32 + o];
            const float wi = WiL[i * 32 + o];
            accr[m] += zr * wr - zi * wi;
            acci[m] += zr * wi + zi * wr;
        }
    }
    const float sck = (kh == 0) ? (1.f / 256.f) : (2.f / 256.f);
    #pragma unroll
    for (int m = 0; m < 8; ++m) {
        const int o = og * 8 + m;
        const size_t zo = ((size_t)(bg * 32 + o) * 32 + kh) * 128 + s;
        Z2[zo]      = accr[m] * sck;
        Z2[zo + 64] = acci[m] * sck;
    }
}

// ---------------------------------------------------------------------------
// K45: per (b,g,o): IDFT_H (mirror, Nyquist) -> YH[256][64] in LDS,
// then IDFT_W (mirror, Nyquist) -> out. bid == output channel index.
// ---------------------------------------------------------------------------
__global__ __launch_bounds__(256) void hw_inv(const float* __restrict__ Z2,
                                              const float* __restrict__ tc,
                                              const float* __restrict__ ts,
                                              float* __restrict__ out) {
    __shared__ float ZL[32 * 128];     // [kh][128] 16 KB
    __shared__ float YH[256 * 64];     // [h][64]  64 KB
    const int bid = blockIdx.x;        // (b*2+g)*32+o == b*64+g*32+o
    const int t = threadIdx.x;
    {
        const float* src = Z2 + (size_t)bid * 4096;
        #pragma unroll
        for (int r = 0; r < 4; ++r) {
            const int f = t + r * 256;
            *(float4*)(ZL + f * 4) = *(const float4*)(src + f * 4);
        }
    }
    __syncthreads();

    // ---- part 1: IDFT_H into YH ----
    {
        const int s = t & 63, hg = t >> 6;
        float zr[32], zi[32];
        #pragma unroll
        for (int k = 0; k < 32; ++k) {
            zr[k] = ZL[k * 128 + s];
            zi[k] = ZL[k * 128 + 64 + s];
        }
        #pragma unroll
        for (int jq = 0; jq < 8; ++jq) {
            const int h0 = hg * 32 + jq * 4;
            float sC[4] = {0, 0, 0, 0}, sS[4] = {0, 0, 0, 0};
            #pragma unroll
            for (int k = 0; k < 32; ++k) {
                const float4 c4 = *(const float4*)(tc + (size_t)k * 256 + h0);
                const float4 s4 = *(const float4*)(ts + (size_t)k * 256 + h0);
                sC[0] += zr[k] * c4.x;  sS[0] += zi[k] * s4.x;
                sC[1] += zr[k] * c4.y;  sS[1] += zi[k] * s4.y;
                sC[2] += zr[k] * c4.z;  sS[2] += zi[k] * s4.z;
                sC[3] += zr[k] * c4.w;  sS[3] += zi[k] * s4.w;
            }
            #pragma unroll
            for (int jj = 0; jj < 4; ++jj) {
                const int h = h0 + jj;
                YH[h * 64 + s] = sC[jj] - sS[jj];
                if (h > 0) YH[(256 - h) * 64 + s] = sC[jj] + sS[jj];
            }
        }
        if (hg == 0) {                 // Nyquist row h = 128
            float ny = 0.f;
            #pragma unroll
            for (int k = 0; k < 32; ++k) ny += (k & 1) ? -zr[k] : zr[k];
            YH[128 * 64 + s] = ny;
        }
    }
    __syncthreads();

    // ---- part 2: IDFT_W per h row -> out ----
    {
        const int w32 = t & 31, hb = t >> 5;   // h = hb*32 + j
        const int w0 = w32 * 4;
        float* outp = out + (size_t)bid * 65536;
        for (int j = 0; j < 32; ++j) {
            const int h = hb * 32 + j;
            const float* yrow = YH + h * 64;
            float sC[4] = {0, 0, 0, 0}, sS[4] = {0, 0, 0, 0};
            #pragma unroll
            for (int kq = 0; kq < 8; ++kq) {
                const float4 R4 = *(const float4*)(yrow + kq * 4);        // uniform
                const float4 I4 = *(const float4*)(yrow + 32 + kq * 4);   // uniform
                const float* tcb = tc + (size_t)(kq * 4) * 256 + w0;
                const float* tsb = ts + (size_t)(kq * 4) * 256 + w0;
                const float4 c0 = *(const float4*)(tcb);
                const float4 s0 = *(const float4*)(tsb);
                const float4 c1 = *(const float4*)(tcb + 256);
                const float4 s1 = *(const float4*)(tsb + 256);
                const float4 c2 = *(const float4*)(tcb + 512);
                const float4 s2 = *(const float4*)(tsb + 512);
                const float4 c3 = *(const float4*)(tcb + 768);
                const float4 s3 = *(const float4*)(tsb + 768);
                sC[0] += R4.x * c0.x + R4.y * c1.x + R4.z * c2.x + R4.w * c3.x;
                sS[0] += I4.x * s0.x + I4.y * s1.x + I4.z * s2.x + I4.w * s3.x;
                sC[1] += R4.x * c0.y + R4.y * c1.y + R4.z * c2.y + R4.w * c3.y;
                sS[1] += I4.x * s0.y + I4.y * s1.y + I4.z * s2.y + I4.w * s3.y;
                sC[2] += R4.x * c0.z + R4.y * c1.z + R4.z * c2.z + R4.w * c3.z;
                sS[2] += I4.x * s0.z + I4.y * s1.z + I4.z * s2.z + I4.w * s3.z;
                sC[3] += R4.x * c0.w + R4.y * c1.w + R4.z * c2.w + R4.w * c3.w;
                sS[3] += I4.x * s0.w + I4.y * s1.w + I4.z * s2.w + I4.w * s3.w;
            }
            *(float4*)(outp + (size_t)h * 256 + w0) =
                make_float4(sC[0] - sS[0], sC[1] - sS[1], sC[2] - sS[2], sC[3] - sS[3]);
            #pragma unroll
            for (int jj = 0; jj < 4; ++jj) {
                const int w = w0 + jj;
                if (w >= 1) outp[(size_t)h * 256 + 256 - w] = sC[jj] + sS[jj];
            }
            if (w32 == 0) {            // Nyquist column w = 128
                float ny = 0.f;
                #pragma unroll
                for (int kq = 0; kq < 8; ++kq) {
                    const float4 R4 = *(const float4*)(yrow + kq * 4);
                    ny += R4.x - R4.y + R4.z - R4.w;
                }
                outp[(size_t)h * 256 + 128] = ny;
            }
        }
    }
}

// ---------------------------------------------------------------------------
extern "C" void kernel_launch(void* const* d_in, const int* in_sizes, int n_in,
                              void* d_out, int out_size, void* d_ws, size_t ws_size,
                              hipStream_t stream) {
    const float* x   = (const float*)d_in[0];
    const float* w1r = (const float*)d_in[1];
    const float* w1i = (const float*)d_in[2];
    const float* w2r = (const float*)d_in[3];
    const float* w2i = (const float*)d_in[4];
    float* out = (float*)d_out;
    float* ws  = (float*)d_ws;

    float* tc = ws;                    //  8192 floats
    float* ts = ws + 8192;             //  8192 floats
    float* Yw = ws + 16384;            //  8,388,608 floats (33.5 MB)
    float* Z  = Yw + 8388608;          //  2,097,152 floats ( 8.4 MB)
    float* Z2 = Z + 2097152;           //  2,097,152 floats ( 8.4 MB)
    // total ws: ~50.4 MB

    init_tab<<<32, 256, 0, stream>>>(tc, ts);
    w_fwd<<<4096, 256, 0, stream>>>(x, w2r, w2i, Yw);
    h_fwd<<<512, 256, 0, stream>>>(Yw, tc, ts, Z);
    h_mix2<<<512, 256, 0, stream>>>(Z, w1r, w1i, Z2);
    hw_inv<<<512, 256, 0, stream>>>(Z2, tc, ts, out);
}

// Round 6
// 216.911 us; speedup vs baseline: 3.1050x; 1.2256x over previous
//
#include <hip/hip_runtime.h>
#include <math.h>

// x: [8][64][256][256] f32 ; w1/w2: [2][32][32][32] f32 (re,im separate)
// Pipeline (all linear ops commute across tensor factors):
//   K1 w_fwd : DFT_W (folded) + mixW -> Yw[c][h][64]   (64 = 32 Re | 32 Im w-modes)
//   K2 h_fwd : DFT_H (folded)        -> Z [bg,kh,o][128] (64 Re_h | 64 Im_h slots)
//   K3 h_mix2: mixH                  -> Z2[c][kh][128]
//   K4 h_inv2: IDFT_H (mirror)       -> YH[c][h][64]   (reuses Yw region)
//   K5 w_inv2: IDFT_W (mirror)       -> out
#define PI2_256 0.0245436926061702596754894014318f  // 2*pi/256

// ---------------------------------------------------------------------------
__global__ __launch_bounds__(256) void init_tab(float* __restrict__ tc, float* __restrict__ ts) {
    int idx = blockIdx.x * 256 + threadIdx.x;   // 0..8191
    int k = idx >> 8, n = idx & 255;            // k < 32
    int m = (k * n) & 255;
    float s, c;
    sincosf(PI2_256 * (float)m, &s, &c);
    tc[idx] = c;
    ts[idx] = s;
}

// ---------------------------------------------------------------------------
// K1: per block = (b,g,xrow). folded DFT_W -> mixW (scale folded) -> global
// ---------------------------------------------------------------------------
__global__ __launch_bounds__(256) void w_fwd(const float* __restrict__ x,
                                             const float* __restrict__ w2r,
                                             const float* __restrict__ w2i,
                                             float* __restrict__ Yw) {
    __shared__ float tile[32 * 256];               // 32 KB; folded in-place
    __shared__ float XrL[32 * 36], XiL[32 * 36];   // [i][k], pad 36

    const int bid  = blockIdx.x;
    const int xrow = bid & 255;
    const int g    = (bid >> 8) & 1;
    const int b    = bid >> 9;
    const int t    = threadIdx.x;

    const size_t chan0 = (size_t)(b * 64 + g * 32);
    const size_t base  = (chan0 * 256 + xrow) * 256;       // + i*65536 + w

    // ---- stage input tile (coalesced float4) ----
    {
        const int wq = t & 63, i0 = t >> 6;
        #pragma unroll
        for (int r = 0; r < 8; ++r) {
            const int i = i0 + r * 4;
            *(float4*)(tile + i * 256 + wq * 4) =
                *(const float4*)(x + base + (size_t)i * 65536 + wq * 4);
        }
    }
    __syncthreads();

    // ---- fold prepass (in place) ----
    {
        const int hq = t & 31, i0 = t >> 5;
        const int h0 = hq * 4;
        float4 a4[4]; float m0[4], m1[4], m2[4], m3[4]; float x128v[4];
        #pragma unroll
        for (int r = 0; r < 4; ++r) {
            const float* row = tile + (i0 + r * 8) * 256;
            a4[r] = *(const float4*)(row + h0);
            m0[r] = row[(256 - (h0 + 0)) & 255];
            m1[r] = row[256 - (h0 + 1)];
            m2[r] = row[256 - (h0 + 2)];
            m3[r] = row[256 - (h0 + 3)];
            x128v[r] = row[128];
        }
        __syncthreads();
        #pragma unroll
        for (int r = 0; r < 4; ++r) {
            float* row = tile + (i0 + r * 8) * 256;
            float4 ye = make_float4(a4[r].x + m0[r], a4[r].y + m1[r],
                                    a4[r].z + m2[r], a4[r].w + m3[r]);
            float4 yo = make_float4(a4[r].x - m0[r], a4[r].y - m1[r],
                                    a4[r].z - m2[r], a4[r].w - m3[r]);
            if (hq == 0) yo.x = x128v[r];                  // stash x128 (s0=0 slot)
            *(float4*)(row + h0)       = ye;
            *(float4*)(row + 128 + h0) = yo;
        }
    }
    __syncthreads();

    // ---- phase A: folded truncated DFT along W, Chebyshev trig ----
    {
        const int k = t & 31, i4 = t >> 5;
        float sd, cd; sincosf(PI2_256 * (float)k, &sd, &cd);
        const float t2 = 2.f * cd;
        float cA = 1.f, sA = 0.f;
        float cB = cd,  sB = -sd;
        const float* r0 = tile + i4 * 256;
        const float* r1 = r0 + 8 * 256;
        const float* r2 = r0 + 16 * 256;
        const float* r3 = r0 + 24 * 256;
        const float x0_0 = r0[0] * 0.5f, x128_0 = r0[128];
        const float x0_1 = r1[0] * 0.5f, x128_1 = r1[128];
        const float x0_2 = r2[0] * 0.5f, x128_2 = r2[128];
        const float x0_3 = r3[0] * 0.5f, x128_3 = r3[128];
        const float sgn = (k & 1) ? -1.f : 1.f;
        float xr0 = sgn * x128_0 - x0_0, xi0 = 0.f;
        float xr1 = sgn * x128_1 - x0_1, xi1 = 0.f;
        float xr2 = sgn * x128_2 - x0_2, xi2 = 0.f;
        float xr3 = sgn * x128_3 - x0_3, xi3 = 0.f;
        for (int hq = 0; hq < 32; ++hq) {
            const float4 yeA = *(const float4*)(r0 + hq * 4);
            const float4 yoA = *(const float4*)(r0 + 128 + hq * 4);
            const float4 yeB = *(const float4*)(r1 + hq * 4);
            const float4 yoB = *(const float4*)(r1 + 128 + hq * 4);
            const float4 yeC = *(const float4*)(r2 + hq * 4);
            const float4 yoC = *(const float4*)(r2 + 128 + hq * 4);
            const float4 yeD = *(const float4*)(r3 + hq * 4);
            const float4 yoD = *(const float4*)(r3 + 128 + hq * 4);
            #pragma unroll
            for (int j = 0; j < 4; ++j) {
                const float c = cA, s = sA;
                xr0 += (&yeA.x)[j] * c;  xi0 -= (&yoA.x)[j] * s;
                xr1 += (&yeB.x)[j] * c;  xi1 -= (&yoB.x)[j] * s;
                xr2 += (&yeC.x)[j] * c;  xi2 -= (&yoC.x)[j] * s;
                xr3 += (&yeD.x)[j] * c;  xi3 -= (&yoD.x)[j] * s;
                const float cn = t2 * cA - cB; cB = cA; cA = cn;
                const float sn = t2 * sA - sB; sB = sA; sA = sn;
            }
        }
        XrL[(i4     ) * 36 + k] = xr0;  XiL[(i4     ) * 36 + k] = xi0;
        XrL[(i4 +  8) * 36 + k] = xr1;  XiL[(i4 +  8) * 36 + k] = xi1;
        XrL[(i4 + 16) * 36 + k] = xr2;  XiL[(i4 + 16) * 36 + k] = xi2;
        XrL[(i4 + 24) * 36 + k] = xr3;  XiL[(i4 + 24) * 36 + k] = xi3;
    }
    __syncthreads();

    // ---- phase B: mixW, scale folded; write 64-real spectral row to global ----
    {
        const int kq = t & 7, o = t >> 3;
        const int k4 = kq * 4;
        float4 ar = {0,0,0,0}, ai = {0,0,0,0};
        const float* wrb = w2r + (size_t)g * 32768 + o * 32 + k4;   // + i*1024
        const float* wib = w2i + (size_t)g * 32768 + o * 32 + k4;
        for (int i = 0; i < 32; ++i) {
            const float4 xr = *(const float4*)(XrL + i * 36 + k4);
            const float4 xi = *(const float4*)(XiL + i * 36 + k4);
            const float4 wr = *(const float4*)(wrb + i * 1024);
            const float4 wi = *(const float4*)(wib + i * 1024);
            ar.x += xr.x * wr.x - xi.x * wi.x;  ai.x += xr.x * wi.x + xi.x * wr.x;
            ar.y += xr.y * wr.y - xi.y * wi.y;  ai.y += xr.y * wi.y + xi.y * wr.y;
            ar.z += xr.z * wr.z - xi.z * wi.z;  ai.z += xr.z * wi.z + xi.z * wr.z;
            ar.w += xr.w * wr.w - xi.w * wi.w;  ai.w += xr.w * wi.w + xi.w * wr.w;
        }
        const float s2 = 2.f / 256.f, s1 = 1.f / 256.f;
        const float s0 = (k4 == 0) ? s1 : s2;
        float* dst = Yw + (size_t)((b * 2 + g) * 32 + o) * 16384 + (size_t)xrow * 64 + k4;
        *(float4*)(dst)      = make_float4(ar.x * s0, ar.y * s2, ar.z * s2, ar.w * s2);
        *(float4*)(dst + 32) = make_float4(ai.x * s0, ai.y * s2, ai.z * s2, ai.w * s2);
    }
}

// ---------------------------------------------------------------------------
// K2: folded DFT_H per channel c. Input Yw[c][h][64] (each slot a real h-signal)
// Z layout: [(bg*32 + kh)*32 + o][128]  (Re_h | Im_h)
// ---------------------------------------------------------------------------
__global__ __launch_bounds__(256) void h_fwd(const float* __restrict__ Yw,
                                             const float* __restrict__ tc,
                                             const float* __restrict__ ts,
                                             float* __restrict__ Z) {
    __shared__ float YL[256 * 64];   // 64 KB
    const int bid = blockIdx.x;      // (b*2+g)*32 + o
    const int t = threadIdx.x;
    {
        const float* src = Yw + (size_t)bid * 16384;
        #pragma unroll
        for (int r = 0; r < 16; ++r) {
            const int f = t + r * 256;
            *(float4*)(YL + f * 4) = *(const float4*)(src + f * 4);
        }
    }
    __syncthreads();

    const int s = t & 63, khg = t >> 6;     // kh = khg*8 + r
    const float y0 = YL[s], y128 = YL[128 * 64 + s];
    float xr[8], xi[8];
    #pragma unroll
    for (int r = 0; r < 8; ++r) {
        xr[r] = ((r & 1) ? -y128 : y128) - y0;
        xi[r] = 0.f;
    }
    const int kb = khg * 8;
    for (int hq = 0; hq < 32; ++hq) {
        float ye[4], yo[4];
        #pragma unroll
        for (int j = 0; j < 4; ++j) {
            const int h = hq * 4 + j;
            const float a = YL[h * 64 + s];
            const float m = YL[((256 - h) & 255) * 64 + s];
            ye[j] = a + m;  yo[j] = a - m;
        }
        #pragma unroll
        for (int r = 0; r < 8; ++r) {
            const float4 c4 = *(const float4*)(tc + (size_t)(kb + r) * 256 + hq * 4);
            const float4 s4 = *(const float4*)(ts + (size_t)(kb + r) * 256 + hq * 4);
            xr[r] += ye[0] * c4.x + ye[1] * c4.y + ye[2] * c4.z + ye[3] * c4.w;
            xi[r] -= yo[0] * s4.x + yo[1] * s4.y + yo[2] * s4.z + yo[3] * s4.w;
        }
    }
    const int o = bid & 31, bg = bid >> 5;
    #pragma unroll
    for (int r = 0; r < 8; ++r) {
        const size_t zi_ = (((size_t)bg * 32 + (kb + r)) * 32 + o) * 128 + s;
        Z[zi_]      = xr[r];
        Z[zi_ + 64] = xi[r];
    }
}

// ---------------------------------------------------------------------------
// K3: mixH per (b,g,kh); H-ortho scale folded. Z2: [(bg*32+o)*32+kh][128]
// ---------------------------------------------------------------------------
__global__ __launch_bounds__(256) void h_mix2(const float* __restrict__ Z,
                                              const float* __restrict__ w1r,
                                              const float* __restrict__ w1i,
                                              float* __restrict__ Z2) {
    __shared__ float ZL[32 * 128];          // [i][128] 16 KB
    __shared__ float WrL[1024], WiL[1024];  // [i*32+o] 8 KB
    const int bid = blockIdx.x;             // bg*32 + kh
    const int kh = bid & 31, bg = bid >> 5;
    const int g = bg & 1;
    const int t = threadIdx.x;
    {
        const float* src = Z + (size_t)bid * 4096;
        #pragma unroll
        for (int r = 0; r < 4; ++r) {
            const int f = t + r * 256;
            *(float4*)(ZL + f * 4) = *(const float4*)(src + f * 4);
        }
        #pragma unroll
        for (int r = 0; r < 4; ++r) {
            const int idx = t + r * 256;    // i = idx>>5, o = idx&31
            const int gidx = g * 32768 + (idx >> 5) * 1024 + (idx & 31) * 32 + kh;
            WrL[idx] = w1r[gidx];
            WiL[idx] = w1i[gidx];
        }
    }
    __syncthreads();

    const int s = t & 63, og = t >> 6;      // o = og*8 + m
    float accr[8], acci[8];
    #pragma unroll
    for (int m = 0; m < 8; ++m) { accr[m] = 0.f; acci[m] = 0.f; }
    for (int i = 0; i < 32; ++i) {
        const float zr = ZL[i * 128 + s];
        const float zi = ZL[i * 128 + 64 + s];
        #pragma unroll
        for (int m = 0; m < 8; ++m) {
            const int o = og * 8 + m;
            const float wr = WrL[i * 32 + o];
            const float wi = WiL[i * 32 + o];
            accr[m] += zr * wr - zi * wi;
            acci[m] += zr * wi + zi * wr;
        }
    }
    const float sck = (kh == 0) ? (1.f / 256.f) : (2.f / 256.f);
    #pragma unroll
    for (int m = 0; m < 8; ++m) {
        const int o = og * 8 + m;
        const size_t zo = ((size_t)(bg * 32 + o) * 32 + kh) * 128 + s;
        Z2[zo]      = accr[m] * sck;
        Z2[zo + 64] = acci[m] * sck;
    }
}

// ---------------------------------------------------------------------------
// K4: IDFT_H (mirror, Nyquist) per channel c. Trig staged in LDS.
// Z2[c][kh][128] -> YHg[c][h][64]   (YHg reuses the Yw region)
// ---------------------------------------------------------------------------
__global__ __launch_bounds__(256) void h_inv2(const float* __restrict__ Z2,
                                              const float* __restrict__ tc,
                                              const float* __restrict__ ts,
                                              float* __restrict__ YHg) {
    __shared__ float ZL[32 * 128];                  // 16 KB
    __shared__ float TcL[32 * 128], TsL[32 * 128];  // 16+16 KB (lower-half trig)
    const int bid = blockIdx.x;                     // channel c
    const int t = threadIdx.x;
    {
        const float* src = Z2 + (size_t)bid * 4096;
        #pragma unroll
        for (int r = 0; r < 4; ++r) {
            const int f = t + r * 256;
            *(float4*)(ZL + f * 4) = *(const float4*)(src + f * 4);
        }
        #pragma unroll
        for (int r = 0; r < 4; ++r) {
            const int q = t + r * 256;              // 0..1023
            const int k = q >> 5, hq = q & 31;
            *(float4*)(TcL + k * 128 + hq * 4) = *(const float4*)(tc + (size_t)k * 256 + hq * 4);
            *(float4*)(TsL + k * 128 + hq * 4) = *(const float4*)(ts + (size_t)k * 256 + hq * 4);
        }
    }
    __syncthreads();

    const int s = t & 63, hg = t >> 6;              // hg 0..3
    float zr[32], zi[32];
    #pragma unroll
    for (int k = 0; k < 32; ++k) {
        zr[k] = ZL[k * 128 + s];
        zi[k] = ZL[k * 128 + 64 + s];
    }
    float* dst = YHg + (size_t)bid * 16384;
    #pragma unroll
    for (int jq = 0; jq < 8; ++jq) {
        const int h0 = hg * 32 + jq * 4;            // 0..124
        float sC[4] = {0, 0, 0, 0}, sS[4] = {0, 0, 0, 0};
        #pragma unroll
        for (int k = 0; k < 32; ++k) {
            const float4 c4 = *(const float4*)(TcL + k * 128 + h0);  // wave-uniform
            const float4 s4 = *(const float4*)(TsL + k * 128 + h0);
            sC[0] += zr[k] * c4.x;  sS[0] += zi[k] * s4.x;
            sC[1] += zr[k] * c4.y;  sS[1] += zi[k] * s4.y;
            sC[2] += zr[k] * c4.z;  sS[2] += zi[k] * s4.z;
            sC[3] += zr[k] * c4.w;  sS[3] += zi[k] * s4.w;
        }
        #pragma unroll
        for (int jj = 0; jj < 4; ++jj) {
            const int h = h0 + jj;
            dst[h * 64 + s] = sC[jj] - sS[jj];
            if (h > 0) dst[(256 - h) * 64 + s] = sC[jj] + sS[jj];
        }
    }
    if (hg == 0) {                                  // Nyquist row h = 128
        float ny = 0.f;
        #pragma unroll
        for (int k = 0; k < 32; ++k) ny += (k & 1) ? -zr[k] : zr[k];
        dst[128 * 64 + s] = ny;
    }
}

// ---------------------------------------------------------------------------
// K5: IDFT_W (mirror, Nyquist). block = (c, hb): 32 h-rows. Trig in LDS.
// YHg[c][h][64] -> out[c][h][256]
// ---------------------------------------------------------------------------
__global__ __launch_bounds__(256) void w_inv2(const float* __restrict__ YHg,
                                              const float* __restrict__ tc,
                                              const float* __restrict__ ts,
                                              float* __restrict__ out) {
    __shared__ float YL[32 * 64];                   // 8 KB  [hl][64]
    __shared__ float TcL[32 * 128], TsL[32 * 128];  // 32 KB (lower-half trig)
    const int bid = blockIdx.x;
    const int hb = bid & 7, c = bid >> 3;
    const int t = threadIdx.x;
    {
        const float* src = YHg + (size_t)c * 16384 + hb * 2048;
        #pragma unroll
        for (int r = 0; r < 2; ++r) {
            const int f = t + r * 256;
            *(float4*)(YL + f * 4) = *(const float4*)(src + f * 4);
        }
        #pragma unroll
        for (int r = 0; r < 4; ++r) {
            const int q = t + r * 256;              // 0..1023
            const int k = q >> 5, wq_ = q & 31;
            *(float4*)(TcL + k * 128 + wq_ * 4) = *(const float4*)(tc + (size_t)k * 256 + wq_ * 4);
            *(float4*)(TsL + k * 128 + wq_ * 4) = *(const float4*)(ts + (size_t)k * 256 + wq_ * 4);
        }
    }
    __syncthreads();

    const int wq = t & 31, hh = t >> 5;             // 4 h-rows per thread
    const int w0 = wq * 4;
    float* outp = out + (size_t)c * 65536;

    float sC[4][4], sS[4][4];                       // [j][w-lane]
    #pragma unroll
    for (int j = 0; j < 4; ++j)
        #pragma unroll
        for (int jj = 0; jj < 4; ++jj) { sC[j][jj] = 0.f; sS[j][jj] = 0.f; }

    for (int k = 0; k < 32; ++k) {
        const float4 c4 = *(const float4*)(TcL + k * 128 + w0);
        const float4 s4 = *(const float4*)(TsL + k * 128 + w0);
        #pragma unroll
        for (int j = 0; j < 4; ++j) {
            const int hl = hh * 4 + j;
            const float R = YL[hl * 64 + k];
            const float I = YL[hl * 64 + 32 + k];
            sC[j][0] += R * c4.x;  sS[j][0] += I * s4.x;
            sC[j][1] += R * c4.y;  sS[j][1] += I * s4.y;
            sC[j][2] += R * c4.z;  sS[j][2] += I * s4.z;
            sC[j][3] += R * c4.w;  sS[j][3] += I * s4.w;
        }
    }
    #pragma unroll
    for (int j = 0; j < 4; ++j) {
        const int h = hb * 32 + hh * 4 + j;
        *(float4*)(outp + (size_t)h * 256 + w0) =
            make_float4(sC[j][0] - sS[j][0], sC[j][1] - sS[j][1],
                        sC[j][2] - sS[j][2], sC[j][3] - sS[j][3]);
        #pragma unroll
        for (int jj = 0; jj < 4; ++jj) {
            const int w = w0 + jj;
            if (w >= 1) outp[(size_t)h * 256 + 256 - w] = sC[j][jj] + sS[j][jj];
        }
    }
    if (wq == 0) {                                  // Nyquist column w = 128
        #pragma unroll
        for (int j = 0; j < 4; ++j) {
            const int hl = hh * 4 + j;
            const int h = hb * 32 + hl;
            float ny = 0.f;
            #pragma unroll
            for (int k = 0; k < 32; ++k) {
                const float R = YL[hl * 64 + k];
                ny += (k & 1) ? -R : R;
            }
            outp[(size_t)h * 256 + 128] = ny;
        }
    }
}

// ---------------------------------------------------------------------------
extern "C" void kernel_launch(void* const* d_in, const int* in_sizes, int n_in,
                              void* d_out, int out_size, void* d_ws, size_t ws_size,
                              hipStream_t stream) {
    const float* x   = (const float*)d_in[0];
    const float* w1r = (const float*)d_in[1];
    const float* w1i = (const float*)d_in[2];
    const float* w2r = (const float*)d_in[3];
    const float* w2i = (const float*)d_in[4];
    float* out = (float*)d_out;
    float* ws  = (float*)d_ws;

    float* tc = ws;                    //  8192 floats
    float* ts = ws + 8192;             //  8192 floats
    float* Yw = ws + 16384;            //  8,388,608 floats (33.5 MB) — reused as YHg
    float* Z  = Yw + 8388608;          //  2,097,152 floats ( 8.4 MB)
    float* Z2 = Z + 2097152;           //  2,097,152 floats ( 8.4 MB)

    init_tab<<<32, 256, 0, stream>>>(tc, ts);
    w_fwd<<<4096, 256, 0, stream>>>(x, w2r, w2i, Yw);
    h_fwd<<<512, 256, 0, stream>>>(Yw, tc, ts, Z);
    h_mix2<<<512, 256, 0, stream>>>(Z, w1r, w1i, Z2);
    h_inv2<<<512, 256, 0, stream>>>(Z2, tc, ts, Yw);   // Yw region reused as YH
    w_inv2<<<4096, 256, 0, stream>>>(Yw, tc, ts, out);
}

// Round 7
// 193.667 us; speedup vs baseline: 3.4777x; 1.1200x over previous
//
#include <hip/hip_runtime.h>
#include <math.h>

// x: [8][64][256][256] f32 ; w1/w2: [2][32][32][32] f32 (re,im separate)
// Pipeline (all linear ops commute across tensor factors):
//   K1 w_fwd : DFT_W (folded) + mixW -> Yw[c][h][64]   (64 = 32 Re | 32 Im w-modes)
//   K2 h_fwd : DFT_H (folded)        -> Z [bg,kh,o][128] (64 Re_h | 64 Im_h slots)
//   K3 h_mix2: mixH                  -> Z2[c][kh][128]
//   K4 h_inv2: IDFT_H (mirror)       -> YH[c][h][64]   (reuses Yw region)
//   K5 w_inv2: IDFT_W (mirror)       -> out
#define PI2_256 0.0245436926061702596754894014318f  // 2*pi/256
#define TS 260                                       // padded tile stride (banks)

// ---------------------------------------------------------------------------
__global__ __launch_bounds__(256) void init_tab(float* __restrict__ tc, float* __restrict__ ts) {
    int idx = blockIdx.x * 256 + threadIdx.x;   // 0..8191
    int k = idx >> 8, n = idx & 255;            // k < 32
    int m = (k * n) & 255;
    float s, c;
    sincosf(PI2_256 * (float)m, &s, &c);
    tc[idx] = c;
    ts[idx] = s;
}

// ---------------------------------------------------------------------------
// K1: per block = (b,g,xrow). folded DFT_W -> mixW (scale folded) -> global
// phase A thread map: hs = t&1 (h-half), kg = (t>>1)&7 (4 k's), rg = t>>4 (2 rows)
// ---------------------------------------------------------------------------
__global__ __launch_bounds__(256) void w_fwd(const float* __restrict__ x,
                                             const float* __restrict__ w2r,
                                             const float* __restrict__ w2i,
                                             float* __restrict__ Yw) {
    __shared__ float tile[32 * TS];                // 33.3 KB; folded in-place
    __shared__ float XrL[32 * 36], XiL[32 * 36];   // [i][k], pad 36

    const int bid  = blockIdx.x;
    const int xrow = bid & 255;
    const int g    = (bid >> 8) & 1;
    const int b    = bid >> 9;
    const int t    = threadIdx.x;

    const size_t chan0 = (size_t)(b * 64 + g * 32);
    const size_t base  = (chan0 * 256 + xrow) * 256;       // + i*65536 + w

    // ---- stage input tile (coalesced float4) ----
    {
        const int wq = t & 63, i0 = t >> 6;
        #pragma unroll
        for (int r = 0; r < 8; ++r) {
            const int i = i0 + r * 4;
            *(float4*)(tile + i * TS + wq * 4) =
                *(const float4*)(x + base + (size_t)i * 65536 + wq * 4);
        }
    }
    __syncthreads();

    // ---- fold prepass (in place): row[0..127]=ye (ye[0]=2x0), row[128]=x128,
    //      row[129..255]=yo ----
    {
        const int hq = t & 31, i0 = t >> 5;
        const int h0 = hq * 4;
        float4 a4[4]; float m0[4], m1[4], m2[4], m3[4]; float x128v[4];
        #pragma unroll
        for (int r = 0; r < 4; ++r) {
            const float* row = tile + (i0 + r * 8) * TS;
            a4[r] = *(const float4*)(row + h0);
            m0[r] = row[(256 - (h0 + 0)) & 255];
            m1[r] = row[256 - (h0 + 1)];
            m2[r] = row[256 - (h0 + 2)];
            m3[r] = row[256 - (h0 + 3)];
            x128v[r] = row[128];
        }
        __syncthreads();
        #pragma unroll
        for (int r = 0; r < 4; ++r) {
            float* row = tile + (i0 + r * 8) * TS;
            float4 ye = make_float4(a4[r].x + m0[r], a4[r].y + m1[r],
                                    a4[r].z + m2[r], a4[r].w + m3[r]);
            float4 yo = make_float4(a4[r].x - m0[r], a4[r].y - m1[r],
                                    a4[r].z - m2[r], a4[r].w - m3[r]);
            if (hq == 0) yo.x = x128v[r];                  // stash x128 (s0=0 slot)
            *(float4*)(row + h0)       = ye;
            *(float4*)(row + 128 + h0) = yo;
        }
    }
    __syncthreads();

    // ---- phase A: folded DFT, Chebyshev; 4 k x 2 rows x h-half per thread ----
    {
        const int hs = t & 1;                    // h-half: h in [hs*64, hs*64+64)
        const int kg = (t >> 1) & 7;             // k = kg + 8*kk
        const int rg = t >> 4;                   // rows 2rg, 2rg+1
        const float* rp0 = tile + (2 * rg) * TS;
        const float* rp1 = rp0 + TS;
        const float sgn = (kg & 1) ? -1.f : 1.f;
        const int hb = hs * 64;

        float cA[4], sA[4], cB[4], sB[4], t2[4];
        float xr[4][2], xi[4][2];
        #pragma unroll
        for (int kk = 0; kk < 4; ++kk) {
            const int k = kg + 8 * kk;
            float sd, cd; sincosf(PI2_256 * (float)k, &sd, &cd);
            t2[kk] = 2.f * cd;
            float ss, cc;
            sincosf(PI2_256 * (float)((k * hb) & 255), &ss, &cc);
            cA[kk] = cc; sA[kk] = ss;
            sincosf(PI2_256 * (float)((k * (hb - 1)) & 255), &ss, &cc);
            cB[kk] = cc; sB[kk] = ss;
        }
        const float x0_0 = rp0[0] * 0.5f, x128_0 = rp0[128];
        const float x0_1 = rp1[0] * 0.5f, x128_1 = rp1[128];
        #pragma unroll
        for (int kk = 0; kk < 4; ++kk) {
            xr[kk][0] = (hs == 0) ? (sgn * x128_0 - x0_0) : 0.f;
            xr[kk][1] = (hs == 0) ? (sgn * x128_1 - x0_1) : 0.f;
            xi[kk][0] = 0.f; xi[kk][1] = 0.f;
        }
        for (int hq = 0; hq < 16; ++hq) {
            const float4 ye0 = *(const float4*)(rp0 + hb + hq * 4);
            const float4 yo0 = *(const float4*)(rp0 + 128 + hb + hq * 4);
            const float4 ye1 = *(const float4*)(rp1 + hb + hq * 4);
            const float4 yo1 = *(const float4*)(rp1 + 128 + hb + hq * 4);
            #pragma unroll
            for (int j = 0; j < 4; ++j) {
                const float e0 = (&ye0.x)[j], o0 = (&yo0.x)[j];
                const float e1 = (&ye1.x)[j], o1 = (&yo1.x)[j];
                #pragma unroll
                for (int kk = 0; kk < 4; ++kk) {
                    xr[kk][0] += e0 * cA[kk];  xi[kk][0] -= o0 * sA[kk];
                    xr[kk][1] += e1 * cA[kk];  xi[kk][1] -= o1 * sA[kk];
                    const float cn = t2[kk] * cA[kk] - cB[kk]; cB[kk] = cA[kk]; cA[kk] = cn;
                    const float sn = t2[kk] * sA[kk] - sB[kk]; sB[kk] = sA[kk]; sA[kk] = sn;
                }
            }
        }
        // combine the two h-halves (lane pairs differ in bit 0)
        #pragma unroll
        for (int kk = 0; kk < 4; ++kk)
            #pragma unroll
            for (int r = 0; r < 2; ++r) {
                xr[kk][r] += __shfl_xor(xr[kk][r], 1);
                xi[kk][r] += __shfl_xor(xi[kk][r], 1);
            }
        if (hs == 0) {
            #pragma unroll
            for (int kk = 0; kk < 4; ++kk) {
                const int k = kg + 8 * kk;
                XrL[(2 * rg    ) * 36 + k] = xr[kk][0];
                XiL[(2 * rg    ) * 36 + k] = xi[kk][0];
                XrL[(2 * rg + 1) * 36 + k] = xr[kk][1];
                XiL[(2 * rg + 1) * 36 + k] = xi[kk][1];
            }
        }
    }
    __syncthreads();

    // ---- phase B: mixW, scale folded; write 64-real spectral row to global ----
    {
        const int kq = t & 7, o = t >> 3;
        const int k4 = kq * 4;
        float4 ar = {0,0,0,0}, ai = {0,0,0,0};
        const float* wrb = w2r + (size_t)g * 32768 + o * 32 + k4;   // + i*1024
        const float* wib = w2i + (size_t)g * 32768 + o * 32 + k4;
        for (int i = 0; i < 32; ++i) {
            const float4 xr = *(const float4*)(XrL + i * 36 + k4);
            const float4 xi = *(const float4*)(XiL + i * 36 + k4);
            const float4 wr = *(const float4*)(wrb + i * 1024);
            const float4 wi = *(const float4*)(wib + i * 1024);
            ar.x += xr.x * wr.x - xi.x * wi.x;  ai.x += xr.x * wi.x + xi.x * wr.x;
            ar.y += xr.y * wr.y - xi.y * wi.y;  ai.y += xr.y * wi.y + xi.y * wr.y;
            ar.z += xr.z * wr.z - xi.z * wi.z;  ai.z += xr.z * wi.z + xi.z * wr.z;
            ar.w += xr.w * wr.w - xi.w * wi.w;  ai.w += xr.w * wi.w + xi.w * wr.w;
        }
        const float s2 = 2.f / 256.f, s1 = 1.f / 256.f;
        const float s0 = (k4 == 0) ? s1 : s2;
        float* dst = Yw + (size_t)((b * 2 + g) * 32 + o) * 16384 + (size_t)xrow * 64 + k4;
        *(float4*)(dst)      = make_float4(ar.x * s0, ar.y * s2, ar.z * s2, ar.w * s2);
        *(float4*)(dst + 32) = make_float4(ai.x * s0, ai.y * s2, ai.z * s2, ai.w * s2);
    }
}

// ---------------------------------------------------------------------------
// K2: folded DFT_H per channel c. Chebyshev trig (no tables).
// thread map: hs = t&1 (h-half), kg = (t>>1)&7 (4 k's), sp = t>>4 (slot quad)
// Z layout: [(bg*32 + kh)*32 + o][128]  (Re_h | Im_h)
// ---------------------------------------------------------------------------
__global__ __launch_bounds__(256) void h_fwd(const float* __restrict__ Yw,
                                             float* __restrict__ Z) {
    __shared__ float YL[256 * 64];   // 64 KB
    const int bid = blockIdx.x;      // (b*2+g)*32 + o
    const int t = threadIdx.x;
    {
        const float* src = Yw + (size_t)bid * 16384;
        #pragma unroll
        for (int r = 0; r < 16; ++r) {
            const int f = t + r * 256;
            *(float4*)(YL + f * 4) = *(const float4*)(src + f * 4);
        }
    }
    __syncthreads();

    const int hs = t & 1, kg = (t >> 1) & 7, sp = t >> 4;  // slots 4sp..4sp+3
    const int hb = hs * 64;
    const float sgn = (kg & 1) ? -1.f : 1.f;
    const float4 y0q   = *(const float4*)(YL + sp * 4);
    const float4 y128q = *(const float4*)(YL + 128 * 64 + sp * 4);

    float cA[4], sA[4], cB[4], sB[4], t2[4];
    float xr[4][4], xi[4][4];
    #pragma unroll
    for (int kk = 0; kk < 4; ++kk) {
        const int k = kg + 8 * kk;
        float sd, cd; sincosf(PI2_256 * (float)k, &sd, &cd);
        t2[kk] = 2.f * cd;
        float ss, cc;
        sincosf(PI2_256 * (float)((k * hb) & 255), &ss, &cc);
        cA[kk] = cc; sA[kk] = ss;
        sincosf(PI2_256 * (float)((k * (hb - 1)) & 255), &ss, &cc);
        cB[kk] = cc; sB[kk] = ss;
        #pragma unroll
        for (int j = 0; j < 4; ++j) {
            xr[kk][j] = (hs == 0) ? (sgn * (&y128q.x)[j] - (&y0q.x)[j]) : 0.f;
            xi[kk][j] = 0.f;
        }
    }
    for (int h = hb; h < hb + 64; ++h) {
        const float4 aq = *(const float4*)(YL + h * 64 + sp * 4);
        const float4 mq = *(const float4*)(YL + ((256 - h) & 255) * 64 + sp * 4);
        float ye[4], yo[4];
        #pragma unroll
        for (int j = 0; j < 4; ++j) {
            ye[j] = (&aq.x)[j] + (&mq.x)[j];
            yo[j] = (&aq.x)[j] - (&mq.x)[j];
        }
        #pragma unroll
        for (int kk = 0; kk < 4; ++kk) {
            #pragma unroll
            for (int j = 0; j < 4; ++j) {
                xr[kk][j] += ye[j] * cA[kk];
                xi[kk][j] -= yo[j] * sA[kk];
            }
            const float cn = t2[kk] * cA[kk] - cB[kk]; cB[kk] = cA[kk]; cA[kk] = cn;
            const float sn = t2[kk] * sA[kk] - sB[kk]; sB[kk] = sA[kk]; sA[kk] = sn;
        }
    }
    // combine h-halves (lane pairs)
    #pragma unroll
    for (int kk = 0; kk < 4; ++kk)
        #pragma unroll
        for (int j = 0; j < 4; ++j) {
            xr[kk][j] += __shfl_xor(xr[kk][j], 1);
            xi[kk][j] += __shfl_xor(xi[kk][j], 1);
        }
    if (hs == 0) {
        const int o = bid & 31, bg = bid >> 5;
        #pragma unroll
        for (int kk = 0; kk < 4; ++kk) {
            const int k = kg + 8 * kk;
            const size_t zi_ = (((size_t)bg * 32 + k) * 32 + o) * 128 + sp * 4;
            *(float4*)(Z + zi_)      = make_float4(xr[kk][0], xr[kk][1], xr[kk][2], xr[kk][3]);
            *(float4*)(Z + zi_ + 64) = make_float4(xi[kk][0], xi[kk][1], xi[kk][2], xi[kk][3]);
        }
    }
}

// ---------------------------------------------------------------------------
// K3: mixH per (b,g,kh); H-ortho scale folded. Z2: [(bg*32+o)*32+kh][128]
// ---------------------------------------------------------------------------
__global__ __launch_bounds__(256) void h_mix2(const float* __restrict__ Z,
                                              const float* __restrict__ w1r,
                                              const float* __restrict__ w1i,
                                              float* __restrict__ Z2) {
    __shared__ float ZL[32 * 128];          // [i][128] 16 KB
    __shared__ float WrL[1024], WiL[1024];  // [i*32+o] 8 KB
    const int bid = blockIdx.x;             // bg*32 + kh
    const int kh = bid & 31, bg = bid >> 5;
    const int g = bg & 1;
    const int t = threadIdx.x;
    {
        const float* src = Z + (size_t)bid * 4096;
        #pragma unroll
        for (int r = 0; r < 4; ++r) {
            const int f = t + r * 256;
            *(float4*)(ZL + f * 4) = *(const float4*)(src + f * 4);
        }
        #pragma unroll
        for (int r = 0; r < 4; ++r) {
            const int idx = t + r * 256;    // i = idx>>5, o = idx&31
            const int gidx = g * 32768 + (idx >> 5) * 1024 + (idx & 31) * 32 + kh;
            WrL[idx] = w1r[gidx];
            WiL[idx] = w1i[gidx];
        }
    }
    __syncthreads();

    const int s = t & 63, og = t >> 6;      // o = og*8 + m
    float accr[8], acci[8];
    #pragma unroll
    for (int m = 0; m < 8; ++m) { accr[m] = 0.f; acci[m] = 0.f; }
    for (int i = 0; i < 32; ++i) {
        const float zr = ZL[i * 128 + s];
        const float zi = ZL[i * 128 + 64 + s];
        #pragma unroll
        for (int m = 0; m < 8; ++m) {
            const int o = og * 8 + m;
            const float wr = WrL[i * 32 + o];
            const float wi = WiL[i * 32 + o];
            accr[m] += zr * wr - zi * wi;
            acci[m] += zr * wi + zi * wr;
        }
    }
    const float sck = (kh == 0) ? (1.f / 256.f) : (2.f / 256.f);
    #pragma unroll
    for (int m = 0; m < 8; ++m) {
        const int o = og * 8 + m;
        const size_t zo = ((size_t)(bg * 32 + o) * 32 + kh) * 128 + s;
        Z2[zo]      = accr[m] * sck;
        Z2[zo + 64] = acci[m] * sck;
    }
}

// ---------------------------------------------------------------------------
// K4: IDFT_H (mirror, Nyquist) per channel c. Trig staged in LDS.
// Z2[c][kh][128] -> YHg[c][h][64]   (YHg reuses the Yw region)
// ---------------------------------------------------------------------------
__global__ __launch_bounds__(256) void h_inv2(const float* __restrict__ Z2,
                                              const float* __restrict__ tc,
                                              const float* __restrict__ ts,
                                              float* __restrict__ YHg) {
    __shared__ float ZL[32 * 128];                  // 16 KB
    __shared__ float TcL[32 * 128], TsL[32 * 128];  // 16+16 KB (lower-half trig)
    const int bid = blockIdx.x;                     // channel c
    const int t = threadIdx.x;
    {
        const float* src = Z2 + (size_t)bid * 4096;
        #pragma unroll
        for (int r = 0; r < 4; ++r) {
            const int f = t + r * 256;
            *(float4*)(ZL + f * 4) = *(const float4*)(src + f * 4);
        }
        #pragma unroll
        for (int r = 0; r < 4; ++r) {
            const int q = t + r * 256;              // 0..1023
            const int k = q >> 5, hq = q & 31;
            *(float4*)(TcL + k * 128 + hq * 4) = *(const float4*)(tc + (size_t)k * 256 + hq * 4);
            *(float4*)(TsL + k * 128 + hq * 4) = *(const float4*)(ts + (size_t)k * 256 + hq * 4);
        }
    }
    __syncthreads();

    const int s = t & 63, hg = t >> 6;              // hg 0..3
    float zr[32], zi[32];
    #pragma unroll
    for (int k = 0; k < 32; ++k) {
        zr[k] = ZL[k * 128 + s];
        zi[k] = ZL[k * 128 + 64 + s];
    }
    float* dst = YHg + (size_t)bid * 16384;
    #pragma unroll
    for (int jq = 0; jq < 8; ++jq) {
        const int h0 = hg * 32 + jq * 4;            // 0..124
        float sC[4] = {0, 0, 0, 0}, sS[4] = {0, 0, 0, 0};
        #pragma unroll
        for (int k = 0; k < 32; ++k) {
            const float4 c4 = *(const float4*)(TcL + k * 128 + h0);  // wave-uniform
            const float4 s4 = *(const float4*)(TsL + k * 128 + h0);
            sC[0] += zr[k] * c4.x;  sS[0] += zi[k] * s4.x;
            sC[1] += zr[k] * c4.y;  sS[1] += zi[k] * s4.y;
            sC[2] += zr[k] * c4.z;  sS[2] += zi[k] * s4.z;
            sC[3] += zr[k] * c4.w;  sS[3] += zi[k] * s4.w;
        }
        #pragma unroll
        for (int jj = 0; jj < 4; ++jj) {
            const int h = h0 + jj;
            dst[h * 64 + s] = sC[jj] - sS[jj];
            if (h > 0) dst[(256 - h) * 64 + s] = sC[jj] + sS[jj];
        }
    }
    if (hg == 0) {                                  // Nyquist row h = 128
        float ny = 0.f;
        #pragma unroll
        for (int k = 0; k < 32; ++k) ny += (k & 1) ? -zr[k] : zr[k];
        dst[128 * 64 + s] = ny;
    }
}

// ---------------------------------------------------------------------------
// K5: IDFT_W (mirror, Nyquist). block = (c, hb): 32 h-rows. Trig in LDS.
// YHg[c][h][64] -> out[c][h][256]
// ---------------------------------------------------------------------------
__global__ __launch_bounds__(256) void w_inv2(const float* __restrict__ YHg,
                                              const float* __restrict__ tc,
                                              const float* __restrict__ ts,
                                              float* __restrict__ out) {
    __shared__ float YL[32 * 64];                   // 8 KB  [hl][64]
    __shared__ float TcL[32 * 128], TsL[32 * 128];  // 32 KB (lower-half trig)
    const int bid = blockIdx.x;
    const int hb = bid & 7, c = bid >> 3;
    const int t = threadIdx.x;
    {
        const float* src = YHg + (size_t)c * 16384 + hb * 2048;
        #pragma unroll
        for (int r = 0; r < 2; ++r) {
            const int f = t + r * 256;
            *(float4*)(YL + f * 4) = *(const float4*)(src + f * 4);
        }
        #pragma unroll
        for (int r = 0; r < 4; ++r) {
            const int q = t + r * 256;              // 0..1023
            const int k = q >> 5, wq_ = q & 31;
            *(float4*)(TcL + k * 128 + wq_ * 4) = *(const float4*)(tc + (size_t)k * 256 + wq_ * 4);
            *(float4*)(TsL + k * 128 + wq_ * 4) = *(const float4*)(ts + (size_t)k * 256 + wq_ * 4);
        }
    }
    __syncthreads();

    const int wq = t & 31, hh = t >> 5;             // 4 h-rows per thread
    const int w0 = wq * 4;
    float* outp = out + (size_t)c * 65536;

    float sC[4][4], sS[4][4];                       // [j][w-lane]
    #pragma unroll
    for (int j = 0; j < 4; ++j)
        #pragma unroll
        for (int jj = 0; jj < 4; ++jj) { sC[j][jj] = 0.f; sS[j][jj] = 0.f; }

    for (int k = 0; k < 32; ++k) {
        const float4 c4 = *(const float4*)(TcL + k * 128 + w0);
        const float4 s4 = *(const float4*)(TsL + k * 128 + w0);
        #pragma unroll
        for (int j = 0; j < 4; ++j) {
            const int hl = hh * 4 + j;
            const float R = YL[hl * 64 + k];
            const float I = YL[hl * 64 + 32 + k];
            sC[j][0] += R * c4.x;  sS[j][0] += I * s4.x;
            sC[j][1] += R * c4.y;  sS[j][1] += I * s4.y;
            sC[j][2] += R * c4.z;  sS[j][2] += I * s4.z;
            sC[j][3] += R * c4.w;  sS[j][3] += I * s4.w;
        }
    }
    #pragma unroll
    for (int j = 0; j < 4; ++j) {
        const int h = hb * 32 + hh * 4 + j;
        *(float4*)(outp + (size_t)h * 256 + w0) =
            make_float4(sC[j][0] - sS[j][0], sC[j][1] - sS[j][1],
                        sC[j][2] - sS[j][2], sC[j][3] - sS[j][3]);
        #pragma unroll
        for (int jj = 0; jj < 4; ++jj) {
            const int w = w0 + jj;
            if (w >= 1) outp[(size_t)h * 256 + 256 - w] = sC[j][jj] + sS[j][jj];
        }
    }
    if (wq == 0) {                                  // Nyquist column w = 128
        #pragma unroll
        for (int j = 0; j < 4; ++j) {
            const int hl = hh * 4 + j;
            const int h = hb * 32 + hl;
            float ny = 0.f;
            #pragma unroll
            for (int k = 0; k < 32; ++k) {
                const float R = YL[hl * 64 + k];
                ny += (k & 1) ? -R : R;
            }
            outp[(size_t)h * 256 + 128] = ny;
        }
    }
}

// ---------------------------------------------------------------------------
extern "C" void kernel_launch(void* const* d_in, const int* in_sizes, int n_in,
                              void* d_out, int out_size, void* d_ws, size_t ws_size,
                              hipStream_t stream) {
    const float* x   = (const float*)d_in[0];
    const float* w1r = (const float*)d_in[1];
    const float* w1i = (const float*)d_in[2];
    const float* w2r = (const float*)d_in[3];
    const float* w2i = (const float*)d_in[4];
    float* out = (float*)d_out;
    float* ws  = (float*)d_ws;

    float* tc = ws;                    //  8192 floats
    float* ts = ws + 8192;             //  8192 floats
    float* Yw = ws + 16384;            //  8,388,608 floats (33.5 MB) — reused as YHg
    float* Z  = Yw + 8388608;          //  2,097,152 floats ( 8.4 MB)
    float* Z2 = Z + 2097152;           //  2,097,152 floats ( 8.4 MB)

    init_tab<<<32, 256, 0, stream>>>(tc, ts);
    w_fwd<<<4096, 256, 0, stream>>>(x, w2r, w2i, Yw);
    h_fwd<<<512, 256, 0, stream>>>(Yw, Z);
    h_mix2<<<512, 256, 0, stream>>>(Z, w1r, w1i, Z2);
    h_inv2<<<512, 256, 0, stream>>>(Z2, tc, ts, Yw);   // Yw region reused as YH
    w_inv2<<<4096, 256, 0, stream>>>(Yw, tc, ts, out);
}